// Round 8
// baseline (925.277 us; speedup 1.0000x reference)
//
#include <hip/hip_runtime.h>
#include <cstdint>
#include <cstddef>

// Problem constants (fixed by setup_inputs)
#define BSZ   4
#define NN    128
#define DD    768
#define HH    8
#define HD    96
#define FFN   3072
#define NNODE (BSZ*NN)    // 512
#define NE    (NNODE*NN)  // 65536

typedef unsigned short u16;
typedef __bf16 bf16x8 __attribute__((ext_vector_type(8)));
typedef float  f32x4  __attribute__((ext_vector_type(4)));
typedef unsigned short u16x8 __attribute__((ext_vector_type(8)));
typedef unsigned short u16x4 __attribute__((ext_vector_type(4)));
typedef unsigned short u16x2 __attribute__((ext_vector_type(2)));

__device__ __forceinline__ float bf2f(u16 a){
    unsigned u = ((unsigned)a) << 16; float f; __builtin_memcpy(&f, &u, 4); return f;
}
__device__ __forceinline__ u16 f2bf(float f){
    unsigned u; __builtin_memcpy(&u, &f, 4);
    u = (u + 0x7fffu + ((u >> 16) & 1u)) >> 16;   // round-to-nearest-even
    return (u16)u;
}
__device__ __forceinline__ f32x4 mfma16(bf16x8 a, bf16x8 b, f32x4 c){
    return __builtin_amdgcn_mfma_f32_16x16x32_bf16(a, b, c, 0, 0, 0);
}
__device__ __forceinline__ bf16x8 frag(const u16* p){
    u16x8 v = *(const u16x8*)p; return __builtin_bit_cast(bf16x8, v);
}
__device__ __forceinline__ float wred_sum(float v){
    #pragma unroll
    for (int m = 1; m < 64; m <<= 1) v += __shfl_xor(v, m);
    return v;
}
__device__ __forceinline__ float wred_max(float v){
    #pragma unroll
    for (int m = 1; m < 64; m <<= 1) v = fmaxf(v, __shfl_xor(v, m));
    return v;
}

// ---------------- LayerNorm (f32 input -> bf16 out) ----------------
__global__ __launch_bounds__(256) void ln_k(const float* __restrict__ in,
                                            const float* __restrict__ sc,
                                            const float* __restrict__ bi,
                                            u16* __restrict__ out){
    int row = blockIdx.x, tid = threadIdx.x;
    const float* r = in + (size_t)row * DD;
    float x0 = r[tid], x1 = r[tid + 256], x2 = r[tid + 512];
    float s = x0 + x1 + x2, q = x0*x0 + x1*x1 + x2*x2;
    s = wred_sum(s); q = wred_sum(q);
    __shared__ float rs[4], rq[4];
    int w = tid >> 6;
    if ((tid & 63) == 0){ rs[w] = s; rq[w] = q; }
    __syncthreads();
    float ts = rs[0] + rs[1] + rs[2] + rs[3];
    float tq = rq[0] + rq[1] + rq[2] + rq[3];
    float mean = ts * (1.f / DD);
    float var  = tq * (1.f / DD) - mean * mean;
    float rstd = rsqrtf(var + 1e-5f);
    u16* o = out + (size_t)row * DD;
    o[tid]       = f2bf((x0 - mean) * rstd * sc[tid]       + bi[tid]);
    o[tid + 256] = f2bf((x1 - mean) * rstd * sc[tid + 256] + bi[tid + 256]);
    o[tid + 512] = f2bf((x2 - mean) * rstd * sc[tid + 512] + bi[tid + 512]);
}

// ---- staging helpers: A tile (bf16 source), B tile (f32 source -> bf16 LDS) ----
__device__ __forceinline__ void stageA(u16* __restrict__ As, const u16* __restrict__ A,
                                       int m0, int lda, int kk, int tid){
    #pragma unroll
    for (int p = 0; p < 2; p++){
        int idx = p * 256 + tid;
        int row = idx >> 3, ch = idx & 7;
        *(uint4*)&As[row * 72 + ch * 8] = *(const uint4*)(A + (size_t)(m0 + row) * lda + kk + ch * 8);
    }
}
__device__ __forceinline__ void stageBf32(u16* __restrict__ Bs, const float* __restrict__ B,
                                          int n0, int ldb, int kk, int tid){
    #pragma unroll
    for (int p = 0; p < 4; p++){
        int idx = p * 256 + tid;
        int row = idx >> 4, c4 = idx & 15;
        float4 v = *(const float4*)(B + (size_t)(n0 + row) * ldb + kk + c4 * 4);
        u16x4 o; o[0] = f2bf(v.x); o[1] = f2bf(v.y); o[2] = f2bf(v.z); o[3] = f2bf(v.w);
        *(u16x4*)&Bs[row * 72 + c4 * 4] = o;
    }
}

// ---------------- Generic GEMM: C[M,N] = A[M,K](bf16) @ B[N,K]^T(f32) + bias -> bf16 ----------------
__global__ __launch_bounds__(256) void gemm_bt(const u16* __restrict__ A, int lda,
                                               const float* __restrict__ B, int ldb,
                                               const float* __restrict__ bias,
                                               u16* __restrict__ C, int ldc, int K){
    __shared__ u16 As[64 * 72];
    __shared__ u16 Bs[64 * 72];
    const int tid = threadIdx.x;
    const int m0 = blockIdx.y * 64, n0 = blockIdx.x * 64;
    const int w = tid >> 6, lane = tid & 63, quad = lane >> 4, l15 = lane & 15;
    const int wy = w >> 1, wx = w & 1;
    f32x4 acc[2][2];
    #pragma unroll
    for (int i = 0; i < 2; i++)
        #pragma unroll
        for (int j = 0; j < 2; j++){ f32x4 z = {0.f,0.f,0.f,0.f}; acc[i][j] = z; }

    for (int kk = 0; kk < K; kk += 64){
        stageA(As, A, m0, lda, kk, tid);
        stageBf32(Bs, B, n0, ldb, kk, tid);
        __syncthreads();
        #pragma unroll
        for (int k0 = 0; k0 < 64; k0 += 32){
            int kb = k0 + quad * 8;
            bf16x8 a0 = frag(&As[(wy * 32 + l15) * 72 + kb]);
            bf16x8 a1 = frag(&As[(wy * 32 + 16 + l15) * 72 + kb]);
            bf16x8 b0 = frag(&Bs[(wx * 32 + l15) * 72 + kb]);
            bf16x8 b1 = frag(&Bs[(wx * 32 + 16 + l15) * 72 + kb]);
            acc[0][0] = mfma16(a0, b0, acc[0][0]);
            acc[0][1] = mfma16(a0, b1, acc[0][1]);
            acc[1][0] = mfma16(a1, b0, acc[1][0]);
            acc[1][1] = mfma16(a1, b1, acc[1][1]);
        }
        __syncthreads();
    }
    #pragma unroll
    for (int j = 0; j < 2; j++){
        int n = n0 + wx * 32 + j * 16 + l15;
        float bv = bias[n];
        #pragma unroll
        for (int i = 0; i < 2; i++){
            #pragma unroll
            for (int r = 0; r < 4; r++){
                int m = m0 + wy * 32 + i * 16 + quad * 4 + r;
                C[(size_t)m * ldc + n] = f2bf(acc[i][j][r] + bv);
            }
        }
    }
}

// ---------------- out-proj GEMM + residual: h1f = att@W^T + b + h (f32 out) ----------------
__global__ __launch_bounds__(256) void gemm_proj(const u16* __restrict__ A,
                                                 const float* __restrict__ B,
                                                 const float* __restrict__ bias,
                                                 const float* __restrict__ h,
                                                 float* __restrict__ h1f){
    __shared__ u16 As[64 * 72];
    __shared__ u16 Bs[64 * 72];
    const int tid = threadIdx.x;
    const int m0 = blockIdx.y * 64, n0 = blockIdx.x * 64;
    const int w = tid >> 6, lane = tid & 63, quad = lane >> 4, l15 = lane & 15;
    const int wy = w >> 1, wx = w & 1;
    f32x4 acc[2][2];
    #pragma unroll
    for (int i = 0; i < 2; i++)
        #pragma unroll
        for (int j = 0; j < 2; j++){ f32x4 z = {0.f,0.f,0.f,0.f}; acc[i][j] = z; }

    for (int kk = 0; kk < DD; kk += 64){
        stageA(As, A, m0, DD, kk, tid);
        stageBf32(Bs, B, n0, DD, kk, tid);
        __syncthreads();
        #pragma unroll
        for (int k0 = 0; k0 < 64; k0 += 32){
            int kb = k0 + quad * 8;
            bf16x8 a0 = frag(&As[(wy * 32 + l15) * 72 + kb]);
            bf16x8 a1 = frag(&As[(wy * 32 + 16 + l15) * 72 + kb]);
            bf16x8 b0 = frag(&Bs[(wx * 32 + l15) * 72 + kb]);
            bf16x8 b1 = frag(&Bs[(wx * 32 + 16 + l15) * 72 + kb]);
            acc[0][0] = mfma16(a0, b0, acc[0][0]);
            acc[0][1] = mfma16(a0, b1, acc[0][1]);
            acc[1][0] = mfma16(a1, b0, acc[1][0]);
            acc[1][1] = mfma16(a1, b1, acc[1][1]);
        }
        __syncthreads();
    }
    #pragma unroll
    for (int j = 0; j < 2; j++){
        int n = n0 + wx * 32 + j * 16 + l15;
        float bv = bias[n];
        #pragma unroll
        for (int i = 0; i < 2; i++){
            #pragma unroll
            for (int r = 0; r < 4; r++){
                int m = m0 + wy * 32 + i * 16 + quad * 4 + r;
                h1f[(size_t)m * DD + n] = acc[i][j][r] + bv + h[(size_t)m * DD + n];
            }
        }
    }
}

// ---------------- GLU GEMM: both halves of y = A@B^T+bias, fused GLU ----------------
// MODE 0: g1 = gelu(a * relu(g)^2)            (bf16, ldc)
// MODE 1: h_out = (a*relu(g)^2 + h1f) * mask  (f32 -> Cf=d_out, bf16 copy -> Cb)
template<int MODE>
__global__ __launch_bounds__(256) void gemm_glu(const u16* __restrict__ A, int lda,
                                                const float* __restrict__ B, int ldb,
                                                const float* __restrict__ bias, int half_off, int K,
                                                const float* __restrict__ h1f,
                                                const float* __restrict__ nodemask,
                                                u16* __restrict__ Cb, int ldc,
                                                float* __restrict__ Cf){
    __shared__ u16 As[64 * 72];
    __shared__ u16 Ba[64 * 72];
    __shared__ u16 Bg[64 * 72];
    const int tid = threadIdx.x;
    const int m0 = blockIdx.y * 64, n0 = blockIdx.x * 64;
    const int w = tid >> 6, lane = tid & 63, quad = lane >> 4, l15 = lane & 15;
    const int wy = w >> 1, wx = w & 1;
    f32x4 accA[2][2], accG[2][2];
    #pragma unroll
    for (int i = 0; i < 2; i++)
        #pragma unroll
        for (int j = 0; j < 2; j++){ f32x4 z = {0.f,0.f,0.f,0.f}; accA[i][j] = z; accG[i][j] = z; }

    for (int kk = 0; kk < K; kk += 64){
        stageA(As, A, m0, lda, kk, tid);
        stageBf32(Ba, B, n0, ldb, kk, tid);
        stageBf32(Bg, B, half_off + n0, ldb, kk, tid);
        __syncthreads();
        #pragma unroll
        for (int k0 = 0; k0 < 64; k0 += 32){
            int kb = k0 + quad * 8;
            bf16x8 a0  = frag(&As[(wy * 32 + l15) * 72 + kb]);
            bf16x8 a1  = frag(&As[(wy * 32 + 16 + l15) * 72 + kb]);
            bf16x8 ba0 = frag(&Ba[(wx * 32 + l15) * 72 + kb]);
            bf16x8 ba1 = frag(&Ba[(wx * 32 + 16 + l15) * 72 + kb]);
            bf16x8 bg0 = frag(&Bg[(wx * 32 + l15) * 72 + kb]);
            bf16x8 bg1 = frag(&Bg[(wx * 32 + 16 + l15) * 72 + kb]);
            accA[0][0] = mfma16(a0, ba0, accA[0][0]);
            accA[0][1] = mfma16(a0, ba1, accA[0][1]);
            accA[1][0] = mfma16(a1, ba0, accA[1][0]);
            accA[1][1] = mfma16(a1, ba1, accA[1][1]);
            accG[0][0] = mfma16(a0, bg0, accG[0][0]);
            accG[0][1] = mfma16(a0, bg1, accG[0][1]);
            accG[1][0] = mfma16(a1, bg0, accG[1][0]);
            accG[1][1] = mfma16(a1, bg1, accG[1][1]);
        }
        __syncthreads();
    }
    #pragma unroll
    for (int j = 0; j < 2; j++){
        int n = n0 + wx * 32 + j * 16 + l15;
        float bva = bias[n];
        float bvg = bias[half_off + n];
        #pragma unroll
        for (int i = 0; i < 2; i++){
            #pragma unroll
            for (int r = 0; r < 4; r++){
                int m = m0 + wy * 32 + i * 16 + quad * 4 + r;
                float a = accA[i][j][r] + bva;
                float g = accG[i][j][r] + bvg;
                float rg = fmaxf(g, 0.f);
                float t = a * rg * rg;
                if (MODE == 0){
                    float v = 0.5f * t * (1.f + erff(t * 0.70710678118654752f));
                    Cb[(size_t)m * ldc + n] = f2bf(v);
                } else {
                    float v = (t + h1f[(size_t)m * DD + n]) * nodemask[m];
                    Cf[(size_t)m * DD + n] = v;
                    Cb[(size_t)m * DD + n] = f2bf(v);
                }
            }
        }
    }
}

// ---------------- PQ GEMM: cm1_w [768 x 1538] f32, strided (row ≡ 8 mod 16 B -> float2) ----------------
__global__ __launch_bounds__(256) void gemm_pq(const u16* __restrict__ A,
                                               const float* __restrict__ W,
                                               const float* __restrict__ bias,
                                               u16* __restrict__ C){
    __shared__ u16 As[64 * 72];
    __shared__ u16 Bp[64 * 72];
    __shared__ u16 Bq[64 * 72];
    const int tid = threadIdx.x;
    const int m0 = blockIdx.y * 64, n0 = blockIdx.x * 64;
    const int w = tid >> 6, lane = tid & 63, quad = lane >> 4, l15 = lane & 15;
    const int wy = w >> 1, wx = w & 1;
    f32x4 accP[2][2], accQ[2][2];
    #pragma unroll
    for (int i = 0; i < 2; i++)
        #pragma unroll
        for (int j = 0; j < 2; j++){ f32x4 z = {0.f,0.f,0.f,0.f}; accP[i][j] = z; accQ[i][j] = z; }

    for (int kk = 0; kk < DD; kk += 64){
        stageA(As, A, m0, DD, kk, tid);
        #pragma unroll
        for (int p = 0; p < 8; p++){
            int idx = p * 256 + tid;
            int row = idx >> 5, c2 = idx & 31;
            size_t base = (size_t)(n0 + row) * 1538 + kk + c2 * 2;
            float2 vp = *(const float2*)(W + base);
            float2 vq = *(const float2*)(W + base + 768);
            u16x2 op; op[0] = f2bf(vp.x); op[1] = f2bf(vp.y);
            u16x2 oq; oq[0] = f2bf(vq.x); oq[1] = f2bf(vq.y);
            *(u16x2*)&Bp[row * 72 + c2 * 2] = op;
            *(u16x2*)&Bq[row * 72 + c2 * 2] = oq;
        }
        __syncthreads();
        #pragma unroll
        for (int k0 = 0; k0 < 64; k0 += 32){
            int kb = k0 + quad * 8;
            bf16x8 a0  = frag(&As[(wy * 32 + l15) * 72 + kb]);
            bf16x8 a1  = frag(&As[(wy * 32 + 16 + l15) * 72 + kb]);
            bf16x8 bp0 = frag(&Bp[(wx * 32 + l15) * 72 + kb]);
            bf16x8 bp1 = frag(&Bp[(wx * 32 + 16 + l15) * 72 + kb]);
            bf16x8 bq0 = frag(&Bq[(wx * 32 + l15) * 72 + kb]);
            bf16x8 bq1 = frag(&Bq[(wx * 32 + 16 + l15) * 72 + kb]);
            accP[0][0] = mfma16(a0, bp0, accP[0][0]);
            accP[0][1] = mfma16(a0, bp1, accP[0][1]);
            accP[1][0] = mfma16(a1, bp0, accP[1][0]);
            accP[1][1] = mfma16(a1, bp1, accP[1][1]);
            accQ[0][0] = mfma16(a0, bq0, accQ[0][0]);
            accQ[0][1] = mfma16(a0, bq1, accQ[0][1]);
            accQ[1][0] = mfma16(a1, bq0, accQ[1][0]);
            accQ[1][1] = mfma16(a1, bq1, accQ[1][1]);
        }
        __syncthreads();
    }
    #pragma unroll
    for (int j = 0; j < 2; j++){
        int n = n0 + wx * 32 + j * 16 + l15;
        float bv = bias[n];
        #pragma unroll
        for (int i = 0; i < 2; i++){
            #pragma unroll
            for (int r = 0; r < 4; r++){
                int m = m0 + wy * 32 + i * 16 + quad * 4 + r;
                C[(size_t)m * 1536 + n]       = f2bf(accP[i][j][r] + bv);
                C[(size_t)m * 1536 + 768 + n] = f2bf(accQ[i][j][r]);
            }
        }
    }
}

// ---------------- Attention v2: one block per (b,h,16-i group), K/V tiles in LDS ----------------
// Stage K,V (128x96 bf16, row stride 98: 49-dword -> conflict-free) with coalesced reads,
// then 16 i-iterations entirely from LDS. Kills the 50M strided scalar global loads of v1.
__global__ __launch_bounds__(128) void attn_k(const u16* __restrict__ qkv,
                                              const float* __restrict__ x,
                                              const float* __restrict__ eattr,
                                              const float* __restrict__ emask,
                                              const float* __restrict__ e1w, const float* __restrict__ e1b,
                                              const float* __restrict__ e2w, const float* __restrict__ e2b,
                                              u16* __restrict__ att){
    __shared__ u16 Ks[NN * 98];
    __shared__ u16 Vs[NN * 98];
    __shared__ float xs[NN * 3];
    __shared__ float qs[HD];
    __shared__ float ps[NN];
    __shared__ float red[2];
    const int tid = threadIdx.x;
    const int h = blockIdx.y, b = blockIdx.z;
    const int i0 = blockIdx.x * 16;

    for (int idx = tid; idx < NN * HD; idx += 128){
        int j = idx / HD, d = idx - j * HD;            // consecutive idx -> consecutive d (coalesced)
        const u16* base = qkv + (size_t)(b * NN + j) * 2304 + h * HD + d;
        Ks[j * 98 + d] = base[DD];
        Vs[j * 98 + d] = base[1536];
    }
    if (tid < NN){
        xs[tid * 3]     = x[(b * NN + tid) * 3];
        xs[tid * 3 + 1] = x[(b * NN + tid) * 3 + 1];
        xs[tid * 3 + 2] = x[(b * NN + tid) * 3 + 2];
    }
    __syncthreads();
    const float w1r = e1w[h * 2], w1a = e1w[h * 2 + 1], b1 = e1b[h];
    const float w2r = e2w[h * 2], w2a = e2w[h * 2 + 1], b2v = e2b[h];
    const int wv = tid >> 6;

    for (int ig = 0; ig < 16; ig++){
        const int i = i0 + ig, ni = b * NN + i;
        if (tid < HD) qs[tid] = bf2f(qkv[(size_t)ni * 2304 + h * HD + tid]) * 0.10206207261596577f;
        __syncthreads();
        const int j = tid;
        float s = 0.f;
        #pragma unroll 8
        for (int d = 0; d < HD; d++) s += qs[d] * bf2f(Ks[j * 98 + d]);
        float d0 = xs[i * 3]     - xs[j * 3];
        float d1 = xs[i * 3 + 1] - xs[j * 3 + 1];
        float d2 = xs[i * 3 + 2] - xs[j * 3 + 2];
        float radial = d0*d0 + d1*d1 + d2*d2;
        int e = ni * NN + j;
        float at = eattr[e], em = emask[e];
        s += (w1r * radial + w1a * at + b1) * em;
        float gw = (w2r * radial + w2a * at + b2v) * em;
        float m1 = wred_max(s);
        if ((tid & 63) == 0) red[wv] = m1;
        __syncthreads();
        float M = fmaxf(red[0], red[1]);
        __syncthreads();
        float ev = __expf(s - M);
        float s1 = wred_sum(ev);
        if ((tid & 63) == 0) red[wv] = s1;
        __syncthreads();
        float S = red[0] + red[1];
        ps[j] = tanhf(gw) * ev / S;
        __syncthreads();
        if (tid < HD){
            float a = 0.f;
            #pragma unroll 8
            for (int jj = 0; jj < NN; jj++) a += ps[jj] * bf2f(Vs[jj * 98 + tid]);
            att[(size_t)ni * DD + h * HD + tid] = f2bf(a);
        }
        __syncthreads();
    }
}

// Extract c0/c1 columns of cm1_w (f32)
__global__ void prep_k(const float* __restrict__ cm1w, float* __restrict__ c01){
    int idx = blockIdx.x * 256 + threadIdx.x;
    if (idx < 768){
        c01[idx]       = cm1w[(size_t)idx * 1538 + 1536];
        c01[768 + idx] = cm1w[(size_t)idx * 1538 + 1537];
    }
}

// Convert f32 array -> bf16 (4 elems/thread)
__global__ void w2bf_k(const float* __restrict__ W, u16* __restrict__ O, int n){
    int i4 = (blockIdx.x * 256 + threadIdx.x) * 4;
    if (i4 < n){
        float4 v = *(const float4*)(W + i4);
        u16x4 o; o[0] = f2bf(v.x); o[1] = f2bf(v.y); o[2] = f2bf(v.z); o[3] = f2bf(v.w);
        *(u16x4*)&O[i4] = o;
    }
}

// ---------------- Edge MLP + coordinate aggregation (v6: v5 + 4 blocks/CU) ----------------
// M=32 per block, kk-outer, no spills (96 acc VGPRs, total 116 <= 128-reg cap at 4 waves/SIMD).
// Round 7 showed 2 blocks/CU is latency-bound on B global loads -> double co-residency.
__global__ __launch_bounds__(256, 4) void edge_k(const u16* __restrict__ PQ,
                                                 const u16* __restrict__ W2b,
                                                 const float* __restrict__ b2,
                                                 const float* __restrict__ w3,
                                                 const float* __restrict__ c01,
                                                 const float* __restrict__ x,
                                                 const float* __restrict__ eattr,
                                                 const float* __restrict__ emask,
                                                 float* __restrict__ aggpart){
    __shared__ u16 T1d[2][32 * 72];     // 9,216 B double buffer
    __shared__ float cdx[32], cdy[32], cdz[32], rad[32], eat[32], ems[32];
    __shared__ float sacc[32];
    const int tid = threadIdx.x;
    const int blk = blockIdx.x;
    const int r = blk >> 2, quarter = blk & 3;
    const int b = r >> 7;
    const int j0 = quarter * 32;

    if (tid < 32){
        int jg = j0 + tid;
        int nc = b * NN + jg;
        int e  = r * NN + jg;
        float d0 = x[r * 3]     - x[nc * 3];
        float d1 = x[r * 3 + 1] - x[nc * 3 + 1];
        float d2 = x[r * 3 + 2] - x[nc * 3 + 2];
        float radial = d0*d0 + d1*d1 + d2*d2;
        float inv = 1.f / (sqrtf(radial + 1e-8f) + 1.0f);   // NORM_CONST = 1
        cdx[tid] = d0 * inv; cdy[tid] = d1 * inv; cdz[tid] = d2 * inv;
        rad[tid] = radial; eat[tid] = eattr[e]; ems[tid] = emask[e];
        sacc[tid] = 0.f;
    }
    __syncthreads();

    // stage T1 K-panel (32 edges x 64 K) for element-offset kk into buffer p: 1 u16x8/thread
    auto stageT1 = [&](int kk, int p){
        int jl = tid >> 3, kc = tid & 7;
        int k = kc * 8;
        int nc = b * NN + j0 + jl;
        u16x8 qv = *(const u16x8*)(PQ + (size_t)nc * 1536 + 768 + kk + k);
        u16x8 pv = *(const u16x8*)(PQ + (size_t)r  * 1536 + kk + k);
        float4 c0a = *(const float4*)(c01 + kk + k);
        float4 c0b = *(const float4*)(c01 + kk + k + 4);
        float4 c1a = *(const float4*)(c01 + 768 + kk + k);
        float4 c1b = *(const float4*)(c01 + 768 + kk + k + 4);
        float c0r[8] = {c0a.x,c0a.y,c0a.z,c0a.w,c0b.x,c0b.y,c0b.z,c0b.w};
        float c1r[8] = {c1a.x,c1a.y,c1a.z,c1a.w,c1b.x,c1b.y,c1b.z,c1b.w};
        float rj = rad[jl], aj = eat[jl];
        u16x8 ov;
        #pragma unroll
        for (int t = 0; t < 8; t++){
            float f = bf2f(pv[t]) + bf2f(qv[t]) + rj * c0r[t] + aj * c1r[t];
            f = f / (1.f + __expf(-f));
            ov[t] = f2bf(f);
        }
        *(u16x8*)&T1d[p][jl * 72 + k] = ov;
    };

    const int w = tid >> 6, lane = tid & 63, quad = lane >> 4, l15 = lane & 15;
    // 3 accumulator sets (one per N-panel), M=32: acc[3][2][4] = 96 VGPRs
    f32x4 acc[3][2][4];
    #pragma unroll
    for (int np = 0; np < 3; np++)
        #pragma unroll
        for (int i = 0; i < 2; i++)
            #pragma unroll
            for (int jj = 0; jj < 4; jj++){ f32x4 z = {0.f,0.f,0.f,0.f}; acc[np][i][jj] = z; }

    stageT1(0, 0);
    __syncthreads();
    for (int kk64 = 0; kk64 < 12; kk64++){
        const int p = kk64 & 1;
        // prefetch next K-panel into the other buffer (overlaps MFMAs below)
        if (kk64 < 11) stageT1((kk64 + 1) * 64, 1 - p);
        const int kbase = kk64 * 64;
        #pragma unroll
        for (int k0 = 0; k0 < 64; k0 += 32){
            const int kq = k0 + quad * 8;
            bf16x8 aF[2];
            #pragma unroll
            for (int i = 0; i < 2; i++) aF[i] = frag(&T1d[p][(i * 16 + l15) * 72 + kq]);
            #pragma unroll
            for (int np = 0; np < 3; np++){
                bf16x8 bF[4];
                #pragma unroll
                for (int jj = 0; jj < 4; jj++)
                    bF[jj] = frag(W2b + (size_t)(np * 256 + w * 64 + jj * 16 + l15) * 768 + kbase + kq);
                #pragma unroll
                for (int i = 0; i < 2; i++)
                    #pragma unroll
                    for (int jj = 0; jj < 4; jj++)
                        acc[np][i][jj] = mfma16(aF[i], bF[jj], acc[np][i][jj]);
            }
        }
        __syncthreads();
    }
    // fused epilogue: silu(t2raw) dot cm3 (b2/w3 from global, L1-hot)
    #pragma unroll
    for (int np = 0; np < 3; np++){
        const int n0 = np * 256;
        float part[2][4];
        #pragma unroll
        for (int i = 0; i < 2; i++)
            #pragma unroll
            for (int rr = 0; rr < 4; rr++) part[i][rr] = 0.f;
        #pragma unroll
        for (int jj = 0; jj < 4; jj++){
            int n = n0 + w * 64 + jj * 16 + l15;
            float bb = b2[n], cc = w3[n];
            #pragma unroll
            for (int i = 0; i < 2; i++)
                #pragma unroll
                for (int rr = 0; rr < 4; rr++){
                    float v = acc[np][i][jj][rr] + bb;
                    v = v / (1.f + __expf(-v));
                    part[i][rr] += v * cc;
                }
        }
        #pragma unroll
        for (int i = 0; i < 2; i++)
            #pragma unroll
            for (int rr = 0; rr < 4; rr++){
                float v = part[i][rr];
                v += __shfl_xor(v, 1); v += __shfl_xor(v, 2);
                v += __shfl_xor(v, 4); v += __shfl_xor(v, 8);
                if (l15 == 0) atomicAdd(&sacc[i * 16 + quad * 4 + rr], v);
            }
    }
    __syncthreads();
    if (tid < 32){
        float sv = sacc[tid] * ems[tid];
        float tx = cdx[tid] * sv, ty = cdy[tid] * sv, tz = cdz[tid] * sv;
        #pragma unroll
        for (int m = 1; m < 32; m <<= 1){
            tx += __shfl_xor(tx, m); ty += __shfl_xor(ty, m); tz += __shfl_xor(tz, m);
        }
        if (tid == 0){
            aggpart[blk * 3 + 0] = tx;
            aggpart[blk * 3 + 1] = ty;
            aggpart[blk * 3 + 2] = tz;
        }
    }
}

__global__ void xout_k(const float* __restrict__ x, const float* __restrict__ linker,
                       const float* __restrict__ nodemask, const float* __restrict__ aggpart,
                       float* __restrict__ out){
    int idx = blockIdx.x * 256 + threadIdx.x;
    if (idx >= NNODE * 3) return;
    int node = idx / 3, c = idx - node * 3;
    float s = aggpart[(node * 4 + 0) * 3 + c] + aggpart[(node * 4 + 1) * 3 + c]
            + aggpart[(node * 4 + 2) * 3 + c] + aggpart[(node * 4 + 3) * 3 + c];
    out[(size_t)NNODE * DD + idx] = (x[idx] + s * 0.01f * linker[node]) * nodemask[node];
}

extern "C" void kernel_launch(void* const* d_in, const int* in_sizes, int n_in,
                              void* d_out, int out_size, void* d_ws, size_t ws_size,
                              hipStream_t stream){
    (void)in_sizes; (void)n_in; (void)out_size; (void)ws_size;
    const float* h        = (const float*)d_in[0];
    const float* x        = (const float*)d_in[1];
    const float* eattr    = (const float*)d_in[2];
    const float* nodemask = (const float*)d_in[3];
    const float* emask    = (const float*)d_in[4];
    const float* linker   = (const float*)d_in[5];
    const float* in_w  = (const float*)d_in[6];  const float* in_b  = (const float*)d_in[7];
    const float* out_w = (const float*)d_in[8];  const float* out_b = (const float*)d_in[9];
    const float* ln1s  = (const float*)d_in[10]; const float* ln1b  = (const float*)d_in[11];
    const float* ln2s  = (const float*)d_in[12]; const float* ln2b  = (const float*)d_in[13];
    const float* fc1w  = (const float*)d_in[14]; const float* fc1b  = (const float*)d_in[15];
    const float* fc2w  = (const float*)d_in[16]; const float* fc2b  = (const float*)d_in[17];
    const float* e1w   = (const float*)d_in[18]; const float* e1b   = (const float*)d_in[19];
    const float* e2w   = (const float*)d_in[20]; const float* e2b   = (const float*)d_in[21];
    const float* cm1w  = (const float*)d_in[22]; const float* cm1b  = (const float*)d_in[23];
    const float* cm2w  = (const float*)d_in[24]; const float* cm2b  = (const float*)d_in[25];
    const float* cm3w  = (const float*)d_in[26];
    // d_in[27] = edge_index (int32): fixed block structure (e = row*128 + j) — used implicitly.
    float* out = (float*)d_out;

    // Workspace layout (peak 7,471,104 B) — lifetimes disjoint:
    char* ws = (char*)d_ws;
    u16*   hn      = (u16*)  (ws + 0);         // [ln1 -> qkv gemm]
    u16*   qkv     = (u16*)  (ws + 786432);    // [qkv gemm -> attn]
    u16*   att     = (u16*)  (ws + 3145728);   // [attn -> proj gemm]
    float* h1f     = (float*)(ws + 0);         // [proj -> glu1]      (hn/qkv dead)
    u16*   ffin    = (u16*)  (ws + 1572864);   // [ln2 -> glu0]
    u16*   g1      = (u16*)  (ws + 2359296);   // [glu0 -> glu1]      (att dead)
    u16*   houtb   = (u16*)  (ws + 5505024);   // [glu1 -> pq gemm]
    u16*   PQ      = (u16*)  (ws + 0);         // [pq gemm -> edge]   (h1f dead)
    float* c01     = (float*)(ws + 1572864);   // [prep -> edge]      (ffin dead)
    float* aggpart = (float*)(ws + 1579008);   // [edge -> xout]      2048*3*4 = 24,576 B
    u16*   cm2b16  = (u16*)  (ws + 6291456);   // [w2bf -> edge]      1.18 MB

    ln_k       <<<NNODE, 256, 0, stream>>>(h, ln1s, ln1b, hn);
    gemm_bt    <<<dim3(2304/64, NNODE/64), 256, 0, stream>>>(hn, DD, in_w, DD, in_b, qkv, 2304, DD);
    attn_k     <<<dim3(NN/16, HH, BSZ), 128, 0, stream>>>(qkv, x, eattr, emask, e1w, e1b, e2w, e2b, att);
    gemm_proj  <<<dim3(DD/64, NNODE/64), 256, 0, stream>>>(att, out_w, out_b, h, h1f);
    ln_k       <<<NNODE, 256, 0, stream>>>(h1f, ln2s, ln2b, ffin);
    gemm_glu<0><<<dim3(FFN/64, NNODE/64), 256, 0, stream>>>(ffin, DD, fc1w, DD, fc1b, FFN, DD,
                                                            nullptr, nullptr, g1, FFN, nullptr);
    gemm_glu<1><<<dim3(DD/64, NNODE/64), 256, 0, stream>>>(g1, FFN, fc2w, FFN, fc2b, DD, FFN,
                                                           h1f, nodemask, houtb, DD, out);
    prep_k     <<<3, 256, 0, stream>>>(cm1w, c01);
    w2bf_k     <<<576, 256, 0, stream>>>(cm2w, cm2b16, DD*DD);
    gemm_pq    <<<dim3(DD/64, NNODE/64), 256, 0, stream>>>(houtb, cm1w, cm1b, PQ);
    edge_k     <<<2048, 256, 0, stream>>>(PQ, cm2b16, cm2b, cm3w, c01, x, eattr, emask, aggpart);
    xout_k     <<<6, 256, 0, stream>>>(x, linker, nodemask, aggpart, out);
}

// Round 9
// 706.227 us; speedup vs baseline: 1.3102x; 1.3102x over previous
//
#include <hip/hip_runtime.h>
#include <cstdint>
#include <cstddef>

// Problem constants (fixed by setup_inputs)
#define BSZ   4
#define NN    128
#define DD    768
#define HH    8
#define HD    96
#define FFN   3072
#define NNODE (BSZ*NN)    // 512
#define NE    (NNODE*NN)  // 65536

typedef unsigned short u16;
typedef __bf16 bf16x8 __attribute__((ext_vector_type(8)));
typedef float  f32x4  __attribute__((ext_vector_type(4)));
typedef unsigned short u16x8 __attribute__((ext_vector_type(8)));
typedef unsigned short u16x4 __attribute__((ext_vector_type(4)));
typedef unsigned short u16x2 __attribute__((ext_vector_type(2)));

__device__ __forceinline__ float bf2f(u16 a){
    unsigned u = ((unsigned)a) << 16; float f; __builtin_memcpy(&f, &u, 4); return f;
}
__device__ __forceinline__ u16 f2bf(float f){
    unsigned u; __builtin_memcpy(&u, &f, 4);
    u = (u + 0x7fffu + ((u >> 16) & 1u)) >> 16;   // round-to-nearest-even
    return (u16)u;
}
__device__ __forceinline__ f32x4 mfma16(bf16x8 a, bf16x8 b, f32x4 c){
    return __builtin_amdgcn_mfma_f32_16x16x32_bf16(a, b, c, 0, 0, 0);
}
__device__ __forceinline__ bf16x8 frag(const u16* p){
    u16x8 v = *(const u16x8*)p; return __builtin_bit_cast(bf16x8, v);
}
__device__ __forceinline__ float wred_sum(float v){
    #pragma unroll
    for (int m = 1; m < 64; m <<= 1) v += __shfl_xor(v, m);
    return v;
}
__device__ __forceinline__ float wred_max(float v){
    #pragma unroll
    for (int m = 1; m < 64; m <<= 1) v = fmaxf(v, __shfl_xor(v, m));
    return v;
}

// ---------------- LayerNorm (f32 input -> bf16 out) ----------------
__global__ __launch_bounds__(256) void ln_k(const float* __restrict__ in,
                                            const float* __restrict__ sc,
                                            const float* __restrict__ bi,
                                            u16* __restrict__ out){
    int row = blockIdx.x, tid = threadIdx.x;
    const float* r = in + (size_t)row * DD;
    float x0 = r[tid], x1 = r[tid + 256], x2 = r[tid + 512];
    float s = x0 + x1 + x2, q = x0*x0 + x1*x1 + x2*x2;
    s = wred_sum(s); q = wred_sum(q);
    __shared__ float rs[4], rq[4];
    int w = tid >> 6;
    if ((tid & 63) == 0){ rs[w] = s; rq[w] = q; }
    __syncthreads();
    float ts = rs[0] + rs[1] + rs[2] + rs[3];
    float tq = rq[0] + rq[1] + rq[2] + rq[3];
    float mean = ts * (1.f / DD);
    float var  = tq * (1.f / DD) - mean * mean;
    float rstd = rsqrtf(var + 1e-5f);
    u16* o = out + (size_t)row * DD;
    o[tid]       = f2bf((x0 - mean) * rstd * sc[tid]       + bi[tid]);
    o[tid + 256] = f2bf((x1 - mean) * rstd * sc[tid + 256] + bi[tid + 256]);
    o[tid + 512] = f2bf((x2 - mean) * rstd * sc[tid + 512] + bi[tid + 512]);
}

// ---- staging helpers: A tile (bf16 source), B tile (f32 source -> bf16 LDS) ----
__device__ __forceinline__ void stageA(u16* __restrict__ As, const u16* __restrict__ A,
                                       int m0, int lda, int kk, int tid){
    #pragma unroll
    for (int p = 0; p < 2; p++){
        int idx = p * 256 + tid;
        int row = idx >> 3, ch = idx & 7;
        *(uint4*)&As[row * 72 + ch * 8] = *(const uint4*)(A + (size_t)(m0 + row) * lda + kk + ch * 8);
    }
}
__device__ __forceinline__ void stageBf32(u16* __restrict__ Bs, const float* __restrict__ B,
                                          int n0, int ldb, int kk, int tid){
    #pragma unroll
    for (int p = 0; p < 4; p++){
        int idx = p * 256 + tid;
        int row = idx >> 4, c4 = idx & 15;
        float4 v = *(const float4*)(B + (size_t)(n0 + row) * ldb + kk + c4 * 4);
        u16x4 o; o[0] = f2bf(v.x); o[1] = f2bf(v.y); o[2] = f2bf(v.z); o[3] = f2bf(v.w);
        *(u16x4*)&Bs[row * 72 + c4 * 4] = o;
    }
}

// ---------------- Generic GEMM: C[M,N] = A[M,K](bf16) @ B[N,K]^T(f32) + bias -> bf16 ----------------
__global__ __launch_bounds__(256) void gemm_bt(const u16* __restrict__ A, int lda,
                                               const float* __restrict__ B, int ldb,
                                               const float* __restrict__ bias,
                                               u16* __restrict__ C, int ldc, int K){
    __shared__ u16 As[64 * 72];
    __shared__ u16 Bs[64 * 72];
    const int tid = threadIdx.x;
    const int m0 = blockIdx.y * 64, n0 = blockIdx.x * 64;
    const int w = tid >> 6, lane = tid & 63, quad = lane >> 4, l15 = lane & 15;
    const int wy = w >> 1, wx = w & 1;
    f32x4 acc[2][2];
    #pragma unroll
    for (int i = 0; i < 2; i++)
        #pragma unroll
        for (int j = 0; j < 2; j++){ f32x4 z = {0.f,0.f,0.f,0.f}; acc[i][j] = z; }

    for (int kk = 0; kk < K; kk += 64){
        stageA(As, A, m0, lda, kk, tid);
        stageBf32(Bs, B, n0, ldb, kk, tid);
        __syncthreads();
        #pragma unroll
        for (int k0 = 0; k0 < 64; k0 += 32){
            int kb = k0 + quad * 8;
            bf16x8 a0 = frag(&As[(wy * 32 + l15) * 72 + kb]);
            bf16x8 a1 = frag(&As[(wy * 32 + 16 + l15) * 72 + kb]);
            bf16x8 b0 = frag(&Bs[(wx * 32 + l15) * 72 + kb]);
            bf16x8 b1 = frag(&Bs[(wx * 32 + 16 + l15) * 72 + kb]);
            acc[0][0] = mfma16(a0, b0, acc[0][0]);
            acc[0][1] = mfma16(a0, b1, acc[0][1]);
            acc[1][0] = mfma16(a1, b0, acc[1][0]);
            acc[1][1] = mfma16(a1, b1, acc[1][1]);
        }
        __syncthreads();
    }
    #pragma unroll
    for (int j = 0; j < 2; j++){
        int n = n0 + wx * 32 + j * 16 + l15;
        float bv = bias[n];
        #pragma unroll
        for (int i = 0; i < 2; i++){
            #pragma unroll
            for (int r = 0; r < 4; r++){
                int m = m0 + wy * 32 + i * 16 + quad * 4 + r;
                C[(size_t)m * ldc + n] = f2bf(acc[i][j][r] + bv);
            }
        }
    }
}

// ---------------- out-proj GEMM + residual: h1f = att@W^T + b + h (f32 out) ----------------
__global__ __launch_bounds__(256) void gemm_proj(const u16* __restrict__ A,
                                                 const float* __restrict__ B,
                                                 const float* __restrict__ bias,
                                                 const float* __restrict__ h,
                                                 float* __restrict__ h1f){
    __shared__ u16 As[64 * 72];
    __shared__ u16 Bs[64 * 72];
    const int tid = threadIdx.x;
    const int m0 = blockIdx.y * 64, n0 = blockIdx.x * 64;
    const int w = tid >> 6, lane = tid & 63, quad = lane >> 4, l15 = lane & 15;
    const int wy = w >> 1, wx = w & 1;
    f32x4 acc[2][2];
    #pragma unroll
    for (int i = 0; i < 2; i++)
        #pragma unroll
        for (int j = 0; j < 2; j++){ f32x4 z = {0.f,0.f,0.f,0.f}; acc[i][j] = z; }

    for (int kk = 0; kk < DD; kk += 64){
        stageA(As, A, m0, DD, kk, tid);
        stageBf32(Bs, B, n0, DD, kk, tid);
        __syncthreads();
        #pragma unroll
        for (int k0 = 0; k0 < 64; k0 += 32){
            int kb = k0 + quad * 8;
            bf16x8 a0 = frag(&As[(wy * 32 + l15) * 72 + kb]);
            bf16x8 a1 = frag(&As[(wy * 32 + 16 + l15) * 72 + kb]);
            bf16x8 b0 = frag(&Bs[(wx * 32 + l15) * 72 + kb]);
            bf16x8 b1 = frag(&Bs[(wx * 32 + 16 + l15) * 72 + kb]);
            acc[0][0] = mfma16(a0, b0, acc[0][0]);
            acc[0][1] = mfma16(a0, b1, acc[0][1]);
            acc[1][0] = mfma16(a1, b0, acc[1][0]);
            acc[1][1] = mfma16(a1, b1, acc[1][1]);
        }
        __syncthreads();
    }
    #pragma unroll
    for (int j = 0; j < 2; j++){
        int n = n0 + wx * 32 + j * 16 + l15;
        float bv = bias[n];
        #pragma unroll
        for (int i = 0; i < 2; i++){
            #pragma unroll
            for (int r = 0; r < 4; r++){
                int m = m0 + wy * 32 + i * 16 + quad * 4 + r;
                h1f[(size_t)m * DD + n] = acc[i][j][r] + bv + h[(size_t)m * DD + n];
            }
        }
    }
}

// ---------------- GLU GEMM: both halves of y = A@B^T+bias, fused GLU ----------------
// MODE 0: g1 = gelu(a * relu(g)^2)            (bf16, ldc)
// MODE 1: h_out = (a*relu(g)^2 + h1f) * mask  (f32 -> Cf=d_out, bf16 copy -> Cb)
template<int MODE>
__global__ __launch_bounds__(256) void gemm_glu(const u16* __restrict__ A, int lda,
                                                const float* __restrict__ B, int ldb,
                                                const float* __restrict__ bias, int half_off, int K,
                                                const float* __restrict__ h1f,
                                                const float* __restrict__ nodemask,
                                                u16* __restrict__ Cb, int ldc,
                                                float* __restrict__ Cf){
    __shared__ u16 As[64 * 72];
    __shared__ u16 Ba[64 * 72];
    __shared__ u16 Bg[64 * 72];
    const int tid = threadIdx.x;
    const int m0 = blockIdx.y * 64, n0 = blockIdx.x * 64;
    const int w = tid >> 6, lane = tid & 63, quad = lane >> 4, l15 = lane & 15;
    const int wy = w >> 1, wx = w & 1;
    f32x4 accA[2][2], accG[2][2];
    #pragma unroll
    for (int i = 0; i < 2; i++)
        #pragma unroll
        for (int j = 0; j < 2; j++){ f32x4 z = {0.f,0.f,0.f,0.f}; accA[i][j] = z; accG[i][j] = z; }

    for (int kk = 0; kk < K; kk += 64){
        stageA(As, A, m0, lda, kk, tid);
        stageBf32(Ba, B, n0, ldb, kk, tid);
        stageBf32(Bg, B, half_off + n0, ldb, kk, tid);
        __syncthreads();
        #pragma unroll
        for (int k0 = 0; k0 < 64; k0 += 32){
            int kb = k0 + quad * 8;
            bf16x8 a0  = frag(&As[(wy * 32 + l15) * 72 + kb]);
            bf16x8 a1  = frag(&As[(wy * 32 + 16 + l15) * 72 + kb]);
            bf16x8 ba0 = frag(&Ba[(wx * 32 + l15) * 72 + kb]);
            bf16x8 ba1 = frag(&Ba[(wx * 32 + 16 + l15) * 72 + kb]);
            bf16x8 bg0 = frag(&Bg[(wx * 32 + l15) * 72 + kb]);
            bf16x8 bg1 = frag(&Bg[(wx * 32 + 16 + l15) * 72 + kb]);
            accA[0][0] = mfma16(a0, ba0, accA[0][0]);
            accA[0][1] = mfma16(a0, ba1, accA[0][1]);
            accA[1][0] = mfma16(a1, ba0, accA[1][0]);
            accA[1][1] = mfma16(a1, ba1, accA[1][1]);
            accG[0][0] = mfma16(a0, bg0, accG[0][0]);
            accG[0][1] = mfma16(a0, bg1, accG[0][1]);
            accG[1][0] = mfma16(a1, bg0, accG[1][0]);
            accG[1][1] = mfma16(a1, bg1, accG[1][1]);
        }
        __syncthreads();
    }
    #pragma unroll
    for (int j = 0; j < 2; j++){
        int n = n0 + wx * 32 + j * 16 + l15;
        float bva = bias[n];
        float bvg = bias[half_off + n];
        #pragma unroll
        for (int i = 0; i < 2; i++){
            #pragma unroll
            for (int r = 0; r < 4; r++){
                int m = m0 + wy * 32 + i * 16 + quad * 4 + r;
                float a = accA[i][j][r] + bva;
                float g = accG[i][j][r] + bvg;
                float rg = fmaxf(g, 0.f);
                float t = a * rg * rg;
                if (MODE == 0){
                    float v = 0.5f * t * (1.f + erff(t * 0.70710678118654752f));
                    Cb[(size_t)m * ldc + n] = f2bf(v);
                } else {
                    float v = (t + h1f[(size_t)m * DD + n]) * nodemask[m];
                    Cf[(size_t)m * DD + n] = v;
                    Cb[(size_t)m * DD + n] = f2bf(v);
                }
            }
        }
    }
}

// ---------------- PQ GEMM: cm1_w [768 x 1538] f32, strided (row ≡ 8 mod 16 B -> float2) ----------------
__global__ __launch_bounds__(256) void gemm_pq(const u16* __restrict__ A,
                                               const float* __restrict__ W,
                                               const float* __restrict__ bias,
                                               u16* __restrict__ C){
    __shared__ u16 As[64 * 72];
    __shared__ u16 Bp[64 * 72];
    __shared__ u16 Bq[64 * 72];
    const int tid = threadIdx.x;
    const int m0 = blockIdx.y * 64, n0 = blockIdx.x * 64;
    const int w = tid >> 6, lane = tid & 63, quad = lane >> 4, l15 = lane & 15;
    const int wy = w >> 1, wx = w & 1;
    f32x4 accP[2][2], accQ[2][2];
    #pragma unroll
    for (int i = 0; i < 2; i++)
        #pragma unroll
        for (int j = 0; j < 2; j++){ f32x4 z = {0.f,0.f,0.f,0.f}; accP[i][j] = z; accQ[i][j] = z; }

    for (int kk = 0; kk < DD; kk += 64){
        stageA(As, A, m0, DD, kk, tid);
        #pragma unroll
        for (int p = 0; p < 8; p++){
            int idx = p * 256 + tid;
            int row = idx >> 5, c2 = idx & 31;
            size_t base = (size_t)(n0 + row) * 1538 + kk + c2 * 2;
            float2 vp = *(const float2*)(W + base);
            float2 vq = *(const float2*)(W + base + 768);
            u16x2 op; op[0] = f2bf(vp.x); op[1] = f2bf(vp.y);
            u16x2 oq; oq[0] = f2bf(vq.x); oq[1] = f2bf(vq.y);
            *(u16x2*)&Bp[row * 72 + c2 * 2] = op;
            *(u16x2*)&Bq[row * 72 + c2 * 2] = oq;
        }
        __syncthreads();
        #pragma unroll
        for (int k0 = 0; k0 < 64; k0 += 32){
            int kb = k0 + quad * 8;
            bf16x8 a0  = frag(&As[(wy * 32 + l15) * 72 + kb]);
            bf16x8 a1  = frag(&As[(wy * 32 + 16 + l15) * 72 + kb]);
            bf16x8 bp0 = frag(&Bp[(wx * 32 + l15) * 72 + kb]);
            bf16x8 bp1 = frag(&Bp[(wx * 32 + 16 + l15) * 72 + kb]);
            bf16x8 bq0 = frag(&Bq[(wx * 32 + l15) * 72 + kb]);
            bf16x8 bq1 = frag(&Bq[(wx * 32 + 16 + l15) * 72 + kb]);
            accP[0][0] = mfma16(a0, bp0, accP[0][0]);
            accP[0][1] = mfma16(a0, bp1, accP[0][1]);
            accP[1][0] = mfma16(a1, bp0, accP[1][0]);
            accP[1][1] = mfma16(a1, bp1, accP[1][1]);
            accQ[0][0] = mfma16(a0, bq0, accQ[0][0]);
            accQ[0][1] = mfma16(a0, bq1, accQ[0][1]);
            accQ[1][0] = mfma16(a1, bq0, accQ[1][0]);
            accQ[1][1] = mfma16(a1, bq1, accQ[1][1]);
        }
        __syncthreads();
    }
    #pragma unroll
    for (int j = 0; j < 2; j++){
        int n = n0 + wx * 32 + j * 16 + l15;
        float bv = bias[n];
        #pragma unroll
        for (int i = 0; i < 2; i++){
            #pragma unroll
            for (int r = 0; r < 4; r++){
                int m = m0 + wy * 32 + i * 16 + quad * 4 + r;
                C[(size_t)m * 1536 + n]       = f2bf(accP[i][j][r] + bv);
                C[(size_t)m * 1536 + 768 + n] = f2bf(accQ[i][j][r]);
            }
        }
    }
}

// ---------------- Attention v2: one block per (b,h,16-i group), K/V tiles in LDS ----------------
__global__ __launch_bounds__(128) void attn_k(const u16* __restrict__ qkv,
                                              const float* __restrict__ x,
                                              const float* __restrict__ eattr,
                                              const float* __restrict__ emask,
                                              const float* __restrict__ e1w, const float* __restrict__ e1b,
                                              const float* __restrict__ e2w, const float* __restrict__ e2b,
                                              u16* __restrict__ att){
    __shared__ u16 Ks[NN * 98];
    __shared__ u16 Vs[NN * 98];
    __shared__ float xs[NN * 3];
    __shared__ float qs[HD];
    __shared__ float ps[NN];
    __shared__ float red[2];
    const int tid = threadIdx.x;
    const int h = blockIdx.y, b = blockIdx.z;
    const int i0 = blockIdx.x * 16;

    for (int idx = tid; idx < NN * HD; idx += 128){
        int j = idx / HD, d = idx - j * HD;
        const u16* base = qkv + (size_t)(b * NN + j) * 2304 + h * HD + d;
        Ks[j * 98 + d] = base[DD];
        Vs[j * 98 + d] = base[1536];
    }
    if (tid < NN){
        xs[tid * 3]     = x[(b * NN + tid) * 3];
        xs[tid * 3 + 1] = x[(b * NN + tid) * 3 + 1];
        xs[tid * 3 + 2] = x[(b * NN + tid) * 3 + 2];
    }
    __syncthreads();
    const float w1r = e1w[h * 2], w1a = e1w[h * 2 + 1], b1 = e1b[h];
    const float w2r = e2w[h * 2], w2a = e2w[h * 2 + 1], b2v = e2b[h];
    const int wv = tid >> 6;

    for (int ig = 0; ig < 16; ig++){
        const int i = i0 + ig, ni = b * NN + i;
        if (tid < HD) qs[tid] = bf2f(qkv[(size_t)ni * 2304 + h * HD + tid]) * 0.10206207261596577f;
        __syncthreads();
        const int j = tid;
        float s = 0.f;
        #pragma unroll 8
        for (int d = 0; d < HD; d++) s += qs[d] * bf2f(Ks[j * 98 + d]);
        float d0 = xs[i * 3]     - xs[j * 3];
        float d1 = xs[i * 3 + 1] - xs[j * 3 + 1];
        float d2 = xs[i * 3 + 2] - xs[j * 3 + 2];
        float radial = d0*d0 + d1*d1 + d2*d2;
        int e = ni * NN + j;
        float at = eattr[e], em = emask[e];
        s += (w1r * radial + w1a * at + b1) * em;
        float gw = (w2r * radial + w2a * at + b2v) * em;
        float m1 = wred_max(s);
        if ((tid & 63) == 0) red[wv] = m1;
        __syncthreads();
        float M = fmaxf(red[0], red[1]);
        __syncthreads();
        float ev = __expf(s - M);
        float s1 = wred_sum(ev);
        if ((tid & 63) == 0) red[wv] = s1;
        __syncthreads();
        float S = red[0] + red[1];
        ps[j] = tanhf(gw) * ev / S;
        __syncthreads();
        if (tid < HD){
            float a = 0.f;
            #pragma unroll 8
            for (int jj = 0; jj < NN; jj++) a += ps[jj] * bf2f(Vs[jj * 98 + tid]);
            att[(size_t)ni * DD + h * HD + tid] = f2bf(a);
        }
        __syncthreads();
    }
}

// Extract c0/c1 columns of cm1_w (f32)
__global__ void prep_k(const float* __restrict__ cm1w, float* __restrict__ c01){
    int idx = blockIdx.x * 256 + threadIdx.x;
    if (idx < 768){
        c01[idx]       = cm1w[(size_t)idx * 1538 + 1536];
        c01[768 + idx] = cm1w[(size_t)idx * 1538 + 1537];
    }
}

// Convert f32 array -> bf16 (4 elems/thread)
__global__ void w2bf_k(const float* __restrict__ W, u16* __restrict__ O, int n){
    int i4 = (blockIdx.x * 256 + threadIdx.x) * 4;
    if (i4 < n){
        float4 v = *(const float4*)(W + i4);
        u16x4 o; o[0] = f2bf(v.x); o[1] = f2bf(v.y); o[2] = f2bf(v.z); o[3] = f2bf(v.w);
        *(u16x4*)&O[i4] = o;
    }
}

// ---------------- Edge MLP + coordinate aggregation (v7: T1 fully resident, barrier-free K-loop) ----------------
// 512 threads (8 waves = 2/SIMD), one block per (row r, half): 64 edges.
// T1 (64x768 bf16, 99 KB LDS) staged ONCE (12 u16x8/thread) -> ONE barrier -> the entire
// 3-np x 12-kk MFMA loop runs barrier-free: aF from read-only LDS, bF direct from L2-hot
// bf16 W2b. acc = 32 f32/thread (np-sequenced). ~100 VGPRs, cap 256 at (512,2): no spill.
__global__ __launch_bounds__(512, 2) void edge_k(const u16* __restrict__ PQ,
                                                 const u16* __restrict__ W2b,
                                                 const float* __restrict__ b2,
                                                 const float* __restrict__ w3,
                                                 const float* __restrict__ c01,
                                                 const float* __restrict__ x,
                                                 const float* __restrict__ eattr,
                                                 const float* __restrict__ emask,
                                                 float* __restrict__ aggpart){
    __shared__ u16 T1[64 * 776];        // 99,328 B
    __shared__ float cdx[64], cdy[64], cdz[64], rad[64], eat[64], ems[64];
    __shared__ float sacc[64];
    const int tid = threadIdx.x;
    const int blk = blockIdx.x;
    const int r = blk >> 1, half = blk & 1;
    const int b = r >> 7;
    const int j0 = half * 64;

    if (tid < 64){
        int jg = j0 + tid;
        int nc = b * NN + jg;
        int e  = r * NN + jg;
        float d0 = x[r * 3]     - x[nc * 3];
        float d1 = x[r * 3 + 1] - x[nc * 3 + 1];
        float d2 = x[r * 3 + 2] - x[nc * 3 + 2];
        float radial = d0*d0 + d1*d1 + d2*d2;
        float inv = 1.f / (sqrtf(radial + 1e-8f) + 1.0f);   // NORM_CONST = 1
        cdx[tid] = d0 * inv; cdy[tid] = d1 * inv; cdz[tid] = d2 * inv;
        rad[tid] = radial; eat[tid] = eattr[e]; ems[tid] = emask[e];
        sacc[tid] = 0.f;
    }
    __syncthreads();

    // stage T1 completely: 64 rows x 96 chunks(x8) = 6144 chunks / 512 threads = 12 per thread
    for (int c = 0; c < 12; c++){
        int idx = c * 512 + tid;
        int jl = idx / 96;
        int kc = idx - jl * 96;
        int k = kc * 8;
        int nc = b * NN + j0 + jl;
        u16x8 qv = *(const u16x8*)(PQ + (size_t)nc * 1536 + 768 + k);
        u16x8 pv = *(const u16x8*)(PQ + (size_t)r  * 1536 + k);
        float4 c0a = *(const float4*)(c01 + k);
        float4 c0b = *(const float4*)(c01 + k + 4);
        float4 c1a = *(const float4*)(c01 + 768 + k);
        float4 c1b = *(const float4*)(c01 + 768 + k + 4);
        float c0r[8] = {c0a.x,c0a.y,c0a.z,c0a.w,c0b.x,c0b.y,c0b.z,c0b.w};
        float c1r[8] = {c1a.x,c1a.y,c1a.z,c1a.w,c1b.x,c1b.y,c1b.z,c1b.w};
        float rj = rad[jl], aj = eat[jl];
        u16x8 ov;
        #pragma unroll
        for (int t = 0; t < 8; t++){
            float f = bf2f(pv[t]) + bf2f(qv[t]) + rj * c0r[t] + aj * c1r[t];
            f = f / (1.f + __expf(-f));
            ov[t] = f2bf(f);
        }
        *(u16x8*)&T1[jl * 776 + k] = ov;
    }
    __syncthreads();   // the ONLY barrier before the epilogue

    // 8 waves: wy = rows (2 groups of 32), wx = cols (4 groups of 64 within each 256-np)
    const int w = tid >> 6, lane = tid & 63, quad = lane >> 4, l15 = lane & 15;
    const int wy = w >> 2, wx = w & 3;
    for (int np = 0; np < 3; np++){
        f32x4 acc[2][4];
        #pragma unroll
        for (int i = 0; i < 2; i++)
            #pragma unroll
            for (int jj = 0; jj < 4; jj++){ f32x4 z = {0.f,0.f,0.f,0.f}; acc[i][jj] = z; }

        #pragma unroll 4
        for (int kk64 = 0; kk64 < 12; kk64++){
            #pragma unroll
            for (int k0 = 0; k0 < 64; k0 += 32){
                const int kq = kk64 * 64 + k0 + quad * 8;
                bf16x8 aF[2], bF[4];
                #pragma unroll
                for (int jj = 0; jj < 4; jj++)
                    bF[jj] = frag(W2b + (size_t)(np * 256 + wx * 64 + jj * 16 + l15) * 768 + kq);
                #pragma unroll
                for (int i = 0; i < 2; i++) aF[i] = frag(&T1[(wy * 32 + i * 16 + l15) * 776 + kq]);
                #pragma unroll
                for (int i = 0; i < 2; i++)
                    #pragma unroll
                    for (int jj = 0; jj < 4; jj++)
                        acc[i][jj] = mfma16(aF[i], bF[jj], acc[i][jj]);
            }
        }
        // fused epilogue: silu(t2raw) dot cm3
        float part[2][4];
        #pragma unroll
        for (int i = 0; i < 2; i++)
            #pragma unroll
            for (int rr = 0; rr < 4; rr++) part[i][rr] = 0.f;
        #pragma unroll
        for (int jj = 0; jj < 4; jj++){
            int n = np * 256 + wx * 64 + jj * 16 + l15;
            float bb = b2[n], cc = w3[n];
            #pragma unroll
            for (int i = 0; i < 2; i++)
                #pragma unroll
                for (int rr = 0; rr < 4; rr++){
                    float v = acc[i][jj][rr] + bb;
                    v = v / (1.f + __expf(-v));
                    part[i][rr] += v * cc;
                }
        }
        #pragma unroll
        for (int i = 0; i < 2; i++)
            #pragma unroll
            for (int rr = 0; rr < 4; rr++){
                float v = part[i][rr];
                v += __shfl_xor(v, 1); v += __shfl_xor(v, 2);
                v += __shfl_xor(v, 4); v += __shfl_xor(v, 8);
                if (l15 == 0) atomicAdd(&sacc[wy * 32 + i * 16 + quad * 4 + rr], v);
            }
    }
    __syncthreads();
    if (tid < 64){
        float sv = sacc[tid] * ems[tid];
        float tx = cdx[tid] * sv, ty = cdy[tid] * sv, tz = cdz[tid] * sv;
        #pragma unroll
        for (int m = 1; m < 64; m <<= 1){
            tx += __shfl_xor(tx, m); ty += __shfl_xor(ty, m); tz += __shfl_xor(tz, m);
        }
        if (tid == 0){
            aggpart[blk * 3 + 0] = tx;
            aggpart[blk * 3 + 1] = ty;
            aggpart[blk * 3 + 2] = tz;
        }
    }
}

__global__ void xout_k(const float* __restrict__ x, const float* __restrict__ linker,
                       const float* __restrict__ nodemask, const float* __restrict__ aggpart,
                       float* __restrict__ out){
    int idx = blockIdx.x * 256 + threadIdx.x;
    if (idx >= NNODE * 3) return;
    int node = idx / 3, c = idx - node * 3;
    float s = aggpart[(node * 2) * 3 + c] + aggpart[(node * 2 + 1) * 3 + c];
    out[(size_t)NNODE * DD + idx] = (x[idx] + s * 0.01f * linker[node]) * nodemask[node];
}

extern "C" void kernel_launch(void* const* d_in, const int* in_sizes, int n_in,
                              void* d_out, int out_size, void* d_ws, size_t ws_size,
                              hipStream_t stream){
    (void)in_sizes; (void)n_in; (void)out_size; (void)ws_size;
    const float* h        = (const float*)d_in[0];
    const float* x        = (const float*)d_in[1];
    const float* eattr    = (const float*)d_in[2];
    const float* nodemask = (const float*)d_in[3];
    const float* emask    = (const float*)d_in[4];
    const float* linker   = (const float*)d_in[5];
    const float* in_w  = (const float*)d_in[6];  const float* in_b  = (const float*)d_in[7];
    const float* out_w = (const float*)d_in[8];  const float* out_b = (const float*)d_in[9];
    const float* ln1s  = (const float*)d_in[10]; const float* ln1b  = (const float*)d_in[11];
    const float* ln2s  = (const float*)d_in[12]; const float* ln2b  = (const float*)d_in[13];
    const float* fc1w  = (const float*)d_in[14]; const float* fc1b  = (const float*)d_in[15];
    const float* fc2w  = (const float*)d_in[16]; const float* fc2b  = (const float*)d_in[17];
    const float* e1w   = (const float*)d_in[18]; const float* e1b   = (const float*)d_in[19];
    const float* e2w   = (const float*)d_in[20]; const float* e2b   = (const float*)d_in[21];
    const float* cm1w  = (const float*)d_in[22]; const float* cm1b  = (const float*)d_in[23];
    const float* cm2w  = (const float*)d_in[24]; const float* cm2b  = (const float*)d_in[25];
    const float* cm3w  = (const float*)d_in[26];
    // d_in[27] = edge_index (int32): fixed block structure (e = row*128 + j) — used implicitly.
    float* out = (float*)d_out;

    // Workspace layout (peak 7,471,104 B) — lifetimes disjoint:
    char* ws = (char*)d_ws;
    u16*   hn      = (u16*)  (ws + 0);         // [ln1 -> qkv gemm]
    u16*   qkv     = (u16*)  (ws + 786432);    // [qkv gemm -> attn]
    u16*   att     = (u16*)  (ws + 3145728);   // [attn -> proj gemm]
    float* h1f     = (float*)(ws + 0);         // [proj -> glu1]      (hn/qkv dead)
    u16*   ffin    = (u16*)  (ws + 1572864);   // [ln2 -> glu0]
    u16*   g1      = (u16*)  (ws + 2359296);   // [glu0 -> glu1]      (att dead)
    u16*   houtb   = (u16*)  (ws + 5505024);   // [glu1 -> pq gemm]
    u16*   PQ      = (u16*)  (ws + 0);         // [pq gemm -> edge]   (h1f dead)
    float* c01     = (float*)(ws + 1572864);   // [prep -> edge]      (ffin dead)
    float* aggpart = (float*)(ws + 1579008);   // [edge -> xout]      1024*3*4 = 12,288 B
    u16*   cm2b16  = (u16*)  (ws + 6291456);   // [w2bf -> edge]      1.18 MB

    ln_k       <<<NNODE, 256, 0, stream>>>(h, ln1s, ln1b, hn);
    gemm_bt    <<<dim3(2304/64, NNODE/64), 256, 0, stream>>>(hn, DD, in_w, DD, in_b, qkv, 2304, DD);
    attn_k     <<<dim3(NN/16, HH, BSZ), 128, 0, stream>>>(qkv, x, eattr, emask, e1w, e1b, e2w, e2b, att);
    gemm_proj  <<<dim3(DD/64, NNODE/64), 256, 0, stream>>>(att, out_w, out_b, h, h1f);
    ln_k       <<<NNODE, 256, 0, stream>>>(h1f, ln2s, ln2b, ffin);
    gemm_glu<0><<<dim3(FFN/64, NNODE/64), 256, 0, stream>>>(ffin, DD, fc1w, DD, fc1b, FFN, DD,
                                                            nullptr, nullptr, g1, FFN, nullptr);
    gemm_glu<1><<<dim3(DD/64, NNODE/64), 256, 0, stream>>>(g1, FFN, fc2w, FFN, fc2b, DD, FFN,
                                                           h1f, nodemask, houtb, DD, out);
    prep_k     <<<3, 256, 0, stream>>>(cm1w, c01);
    w2bf_k     <<<576, 256, 0, stream>>>(cm2w, cm2b16, DD*DD);
    gemm_pq    <<<dim3(DD/64, NNODE/64), 256, 0, stream>>>(houtb, cm1w, cm1b, PQ);
    edge_k     <<<1024, 512, 0, stream>>>(PQ, cm2b16, cm2b, cm3w, c01, x, eattr, emask, aggpart);
    xout_k     <<<6, 256, 0, stream>>>(x, linker, nodemask, aggpart, out);
}

// Round 10
// 558.991 us; speedup vs baseline: 1.6553x; 1.2634x over previous
//
#include <hip/hip_runtime.h>
#include <cstdint>
#include <cstddef>

// Problem constants (fixed by setup_inputs)
#define BSZ   4
#define NN    128
#define DD    768
#define HH    8
#define HD    96
#define FFN   3072
#define NNODE (BSZ*NN)    // 512
#define NE    (NNODE*NN)  // 65536

typedef unsigned short u16;
typedef __bf16 bf16x8 __attribute__((ext_vector_type(8)));
typedef float  f32x4  __attribute__((ext_vector_type(4)));
typedef unsigned short u16x8 __attribute__((ext_vector_type(8)));
typedef unsigned short u16x4 __attribute__((ext_vector_type(4)));
typedef unsigned short u16x2 __attribute__((ext_vector_type(2)));

__device__ __forceinline__ float bf2f(u16 a){
    unsigned u = ((unsigned)a) << 16; float f; __builtin_memcpy(&f, &u, 4); return f;
}
__device__ __forceinline__ u16 f2bf(float f){
    unsigned u; __builtin_memcpy(&u, &f, 4);
    u = (u + 0x7fffu + ((u >> 16) & 1u)) >> 16;   // round-to-nearest-even
    return (u16)u;
}
__device__ __forceinline__ f32x4 mfma16(bf16x8 a, bf16x8 b, f32x4 c){
    return __builtin_amdgcn_mfma_f32_16x16x32_bf16(a, b, c, 0, 0, 0);
}
__device__ __forceinline__ bf16x8 frag(const u16* p){
    u16x8 v = *(const u16x8*)p; return __builtin_bit_cast(bf16x8, v);
}
__device__ __forceinline__ float wred_sum(float v){
    #pragma unroll
    for (int m = 1; m < 64; m <<= 1) v += __shfl_xor(v, m);
    return v;
}
__device__ __forceinline__ float wred_max(float v){
    #pragma unroll
    for (int m = 1; m < 64; m <<= 1) v = fmaxf(v, __shfl_xor(v, m));
    return v;
}

// ---------------- LayerNorm (f32 input -> bf16 out) ----------------
__global__ __launch_bounds__(256) void ln_k(const float* __restrict__ in,
                                            const float* __restrict__ sc,
                                            const float* __restrict__ bi,
                                            u16* __restrict__ out){
    int row = blockIdx.x, tid = threadIdx.x;
    const float* r = in + (size_t)row * DD;
    float x0 = r[tid], x1 = r[tid + 256], x2 = r[tid + 512];
    float s = x0 + x1 + x2, q = x0*x0 + x1*x1 + x2*x2;
    s = wred_sum(s); q = wred_sum(q);
    __shared__ float rs[4], rq[4];
    int w = tid >> 6;
    if ((tid & 63) == 0){ rs[w] = s; rq[w] = q; }
    __syncthreads();
    float ts = rs[0] + rs[1] + rs[2] + rs[3];
    float tq = rq[0] + rq[1] + rq[2] + rq[3];
    float mean = ts * (1.f / DD);
    float var  = tq * (1.f / DD) - mean * mean;
    float rstd = rsqrtf(var + 1e-5f);
    u16* o = out + (size_t)row * DD;
    o[tid]       = f2bf((x0 - mean) * rstd * sc[tid]       + bi[tid]);
    o[tid + 256] = f2bf((x1 - mean) * rstd * sc[tid + 256] + bi[tid + 256]);
    o[tid + 512] = f2bf((x2 - mean) * rstd * sc[tid + 512] + bi[tid + 512]);
}

// ---- staging helpers: A tile (bf16 source), B tile (f32 source -> bf16 LDS) ----
__device__ __forceinline__ void stageA(u16* __restrict__ As, const u16* __restrict__ A,
                                       int m0, int lda, int kk, int tid){
    #pragma unroll
    for (int p = 0; p < 2; p++){
        int idx = p * 256 + tid;
        int row = idx >> 3, ch = idx & 7;
        *(uint4*)&As[row * 72 + ch * 8] = *(const uint4*)(A + (size_t)(m0 + row) * lda + kk + ch * 8);
    }
}
__device__ __forceinline__ void stageBf32(u16* __restrict__ Bs, const float* __restrict__ B,
                                          int n0, int ldb, int kk, int tid){
    #pragma unroll
    for (int p = 0; p < 4; p++){
        int idx = p * 256 + tid;
        int row = idx >> 4, c4 = idx & 15;
        float4 v = *(const float4*)(B + (size_t)(n0 + row) * ldb + kk + c4 * 4);
        u16x4 o; o[0] = f2bf(v.x); o[1] = f2bf(v.y); o[2] = f2bf(v.z); o[3] = f2bf(v.w);
        *(u16x4*)&Bs[row * 72 + c4 * 4] = o;
    }
}

// ---------------- Generic GEMM: C[M,N] = A[M,K](bf16) @ B[N,K]^T(f32) + bias -> bf16 ----------------
__global__ __launch_bounds__(256) void gemm_bt(const u16* __restrict__ A, int lda,
                                               const float* __restrict__ B, int ldb,
                                               const float* __restrict__ bias,
                                               u16* __restrict__ C, int ldc, int K){
    __shared__ u16 As[64 * 72];
    __shared__ u16 Bs[64 * 72];
    const int tid = threadIdx.x;
    const int m0 = blockIdx.y * 64, n0 = blockIdx.x * 64;
    const int w = tid >> 6, lane = tid & 63, quad = lane >> 4, l15 = lane & 15;
    const int wy = w >> 1, wx = w & 1;
    f32x4 acc[2][2];
    #pragma unroll
    for (int i = 0; i < 2; i++)
        #pragma unroll
        for (int j = 0; j < 2; j++){ f32x4 z = {0.f,0.f,0.f,0.f}; acc[i][j] = z; }

    for (int kk = 0; kk < K; kk += 64){
        stageA(As, A, m0, lda, kk, tid);
        stageBf32(Bs, B, n0, ldb, kk, tid);
        __syncthreads();
        #pragma unroll
        for (int k0 = 0; k0 < 64; k0 += 32){
            int kb = k0 + quad * 8;
            bf16x8 a0 = frag(&As[(wy * 32 + l15) * 72 + kb]);
            bf16x8 a1 = frag(&As[(wy * 32 + 16 + l15) * 72 + kb]);
            bf16x8 b0 = frag(&Bs[(wx * 32 + l15) * 72 + kb]);
            bf16x8 b1 = frag(&Bs[(wx * 32 + 16 + l15) * 72 + kb]);
            acc[0][0] = mfma16(a0, b0, acc[0][0]);
            acc[0][1] = mfma16(a0, b1, acc[0][1]);
            acc[1][0] = mfma16(a1, b0, acc[1][0]);
            acc[1][1] = mfma16(a1, b1, acc[1][1]);
        }
        __syncthreads();
    }
    #pragma unroll
    for (int j = 0; j < 2; j++){
        int n = n0 + wx * 32 + j * 16 + l15;
        float bv = bias[n];
        #pragma unroll
        for (int i = 0; i < 2; i++){
            #pragma unroll
            for (int r = 0; r < 4; r++){
                int m = m0 + wy * 32 + i * 16 + quad * 4 + r;
                C[(size_t)m * ldc + n] = f2bf(acc[i][j][r] + bv);
            }
        }
    }
}

// ---------------- out-proj GEMM + residual: h1f = att@W^T + b + h (f32 out) ----------------
__global__ __launch_bounds__(256) void gemm_proj(const u16* __restrict__ A,
                                                 const float* __restrict__ B,
                                                 const float* __restrict__ bias,
                                                 const float* __restrict__ h,
                                                 float* __restrict__ h1f){
    __shared__ u16 As[64 * 72];
    __shared__ u16 Bs[64 * 72];
    const int tid = threadIdx.x;
    const int m0 = blockIdx.y * 64, n0 = blockIdx.x * 64;
    const int w = tid >> 6, lane = tid & 63, quad = lane >> 4, l15 = lane & 15;
    const int wy = w >> 1, wx = w & 1;
    f32x4 acc[2][2];
    #pragma unroll
    for (int i = 0; i < 2; i++)
        #pragma unroll
        for (int j = 0; j < 2; j++){ f32x4 z = {0.f,0.f,0.f,0.f}; acc[i][j] = z; }

    for (int kk = 0; kk < DD; kk += 64){
        stageA(As, A, m0, DD, kk, tid);
        stageBf32(Bs, B, n0, DD, kk, tid);
        __syncthreads();
        #pragma unroll
        for (int k0 = 0; k0 < 64; k0 += 32){
            int kb = k0 + quad * 8;
            bf16x8 a0 = frag(&As[(wy * 32 + l15) * 72 + kb]);
            bf16x8 a1 = frag(&As[(wy * 32 + 16 + l15) * 72 + kb]);
            bf16x8 b0 = frag(&Bs[(wx * 32 + l15) * 72 + kb]);
            bf16x8 b1 = frag(&Bs[(wx * 32 + 16 + l15) * 72 + kb]);
            acc[0][0] = mfma16(a0, b0, acc[0][0]);
            acc[0][1] = mfma16(a0, b1, acc[0][1]);
            acc[1][0] = mfma16(a1, b0, acc[1][0]);
            acc[1][1] = mfma16(a1, b1, acc[1][1]);
        }
        __syncthreads();
    }
    #pragma unroll
    for (int j = 0; j < 2; j++){
        int n = n0 + wx * 32 + j * 16 + l15;
        float bv = bias[n];
        #pragma unroll
        for (int i = 0; i < 2; i++){
            #pragma unroll
            for (int r = 0; r < 4; r++){
                int m = m0 + wy * 32 + i * 16 + quad * 4 + r;
                h1f[(size_t)m * DD + n] = acc[i][j][r] + bv + h[(size_t)m * DD + n];
            }
        }
    }
}

// ---------------- GLU GEMM: both halves of y = A@B^T+bias, fused GLU ----------------
// MODE 0: g1 = gelu(a * relu(g)^2)            (bf16, ldc)
// MODE 1: h_out = (a*relu(g)^2 + h1f) * mask  (f32 -> Cf=d_out, bf16 copy -> Cb)
template<int MODE>
__global__ __launch_bounds__(256) void gemm_glu(const u16* __restrict__ A, int lda,
                                                const float* __restrict__ B, int ldb,
                                                const float* __restrict__ bias, int half_off, int K,
                                                const float* __restrict__ h1f,
                                                const float* __restrict__ nodemask,
                                                u16* __restrict__ Cb, int ldc,
                                                float* __restrict__ Cf){
    __shared__ u16 As[64 * 72];
    __shared__ u16 Ba[64 * 72];
    __shared__ u16 Bg[64 * 72];
    const int tid = threadIdx.x;
    const int m0 = blockIdx.y * 64, n0 = blockIdx.x * 64;
    const int w = tid >> 6, lane = tid & 63, quad = lane >> 4, l15 = lane & 15;
    const int wy = w >> 1, wx = w & 1;
    f32x4 accA[2][2], accG[2][2];
    #pragma unroll
    for (int i = 0; i < 2; i++)
        #pragma unroll
        for (int j = 0; j < 2; j++){ f32x4 z = {0.f,0.f,0.f,0.f}; accA[i][j] = z; accG[i][j] = z; }

    for (int kk = 0; kk < K; kk += 64){
        stageA(As, A, m0, lda, kk, tid);
        stageBf32(Ba, B, n0, ldb, kk, tid);
        stageBf32(Bg, B, half_off + n0, ldb, kk, tid);
        __syncthreads();
        #pragma unroll
        for (int k0 = 0; k0 < 64; k0 += 32){
            int kb = k0 + quad * 8;
            bf16x8 a0  = frag(&As[(wy * 32 + l15) * 72 + kb]);
            bf16x8 a1  = frag(&As[(wy * 32 + 16 + l15) * 72 + kb]);
            bf16x8 ba0 = frag(&Ba[(wx * 32 + l15) * 72 + kb]);
            bf16x8 ba1 = frag(&Ba[(wx * 32 + 16 + l15) * 72 + kb]);
            bf16x8 bg0 = frag(&Bg[(wx * 32 + l15) * 72 + kb]);
            bf16x8 bg1 = frag(&Bg[(wx * 32 + 16 + l15) * 72 + kb]);
            accA[0][0] = mfma16(a0, ba0, accA[0][0]);
            accA[0][1] = mfma16(a0, ba1, accA[0][1]);
            accA[1][0] = mfma16(a1, ba0, accA[1][0]);
            accA[1][1] = mfma16(a1, ba1, accA[1][1]);
            accG[0][0] = mfma16(a0, bg0, accG[0][0]);
            accG[0][1] = mfma16(a0, bg1, accG[0][1]);
            accG[1][0] = mfma16(a1, bg0, accG[1][0]);
            accG[1][1] = mfma16(a1, bg1, accG[1][1]);
        }
        __syncthreads();
    }
    #pragma unroll
    for (int j = 0; j < 2; j++){
        int n = n0 + wx * 32 + j * 16 + l15;
        float bva = bias[n];
        float bvg = bias[half_off + n];
        #pragma unroll
        for (int i = 0; i < 2; i++){
            #pragma unroll
            for (int r = 0; r < 4; r++){
                int m = m0 + wy * 32 + i * 16 + quad * 4 + r;
                float a = accA[i][j][r] + bva;
                float g = accG[i][j][r] + bvg;
                float rg = fmaxf(g, 0.f);
                float t = a * rg * rg;
                if (MODE == 0){
                    float v = 0.5f * t * (1.f + erff(t * 0.70710678118654752f));
                    Cb[(size_t)m * ldc + n] = f2bf(v);
                } else {
                    float v = (t + h1f[(size_t)m * DD + n]) * nodemask[m];
                    Cf[(size_t)m * DD + n] = v;
                    Cb[(size_t)m * DD + n] = f2bf(v);
                }
            }
        }
    }
}

// ---------------- PQ GEMM: cm1_w [768 x 1538] f32, strided (row ≡ 8 mod 16 B -> float2) ----------------
__global__ __launch_bounds__(256) void gemm_pq(const u16* __restrict__ A,
                                               const float* __restrict__ W,
                                               const float* __restrict__ bias,
                                               u16* __restrict__ C){
    __shared__ u16 As[64 * 72];
    __shared__ u16 Bp[64 * 72];
    __shared__ u16 Bq[64 * 72];
    const int tid = threadIdx.x;
    const int m0 = blockIdx.y * 64, n0 = blockIdx.x * 64;
    const int w = tid >> 6, lane = tid & 63, quad = lane >> 4, l15 = lane & 15;
    const int wy = w >> 1, wx = w & 1;
    f32x4 accP[2][2], accQ[2][2];
    #pragma unroll
    for (int i = 0; i < 2; i++)
        #pragma unroll
        for (int j = 0; j < 2; j++){ f32x4 z = {0.f,0.f,0.f,0.f}; accP[i][j] = z; accQ[i][j] = z; }

    for (int kk = 0; kk < DD; kk += 64){
        stageA(As, A, m0, DD, kk, tid);
        #pragma unroll
        for (int p = 0; p < 8; p++){
            int idx = p * 256 + tid;
            int row = idx >> 5, c2 = idx & 31;
            size_t base = (size_t)(n0 + row) * 1538 + kk + c2 * 2;
            float2 vp = *(const float2*)(W + base);
            float2 vq = *(const float2*)(W + base + 768);
            u16x2 op; op[0] = f2bf(vp.x); op[1] = f2bf(vp.y);
            u16x2 oq; oq[0] = f2bf(vq.x); oq[1] = f2bf(vq.y);
            *(u16x2*)&Bp[row * 72 + c2 * 2] = op;
            *(u16x2*)&Bq[row * 72 + c2 * 2] = oq;
        }
        __syncthreads();
        #pragma unroll
        for (int k0 = 0; k0 < 64; k0 += 32){
            int kb = k0 + quad * 8;
            bf16x8 a0  = frag(&As[(wy * 32 + l15) * 72 + kb]);
            bf16x8 a1  = frag(&As[(wy * 32 + 16 + l15) * 72 + kb]);
            bf16x8 bp0 = frag(&Bp[(wx * 32 + l15) * 72 + kb]);
            bf16x8 bp1 = frag(&Bp[(wx * 32 + 16 + l15) * 72 + kb]);
            bf16x8 bq0 = frag(&Bq[(wx * 32 + l15) * 72 + kb]);
            bf16x8 bq1 = frag(&Bq[(wx * 32 + 16 + l15) * 72 + kb]);
            accP[0][0] = mfma16(a0, bp0, accP[0][0]);
            accP[0][1] = mfma16(a0, bp1, accP[0][1]);
            accP[1][0] = mfma16(a1, bp0, accP[1][0]);
            accP[1][1] = mfma16(a1, bp1, accP[1][1]);
            accQ[0][0] = mfma16(a0, bq0, accQ[0][0]);
            accQ[0][1] = mfma16(a0, bq1, accQ[0][1]);
            accQ[1][0] = mfma16(a1, bq0, accQ[1][0]);
            accQ[1][1] = mfma16(a1, bq1, accQ[1][1]);
        }
        __syncthreads();
    }
    #pragma unroll
    for (int j = 0; j < 2; j++){
        int n = n0 + wx * 32 + j * 16 + l15;
        float bv = bias[n];
        #pragma unroll
        for (int i = 0; i < 2; i++){
            #pragma unroll
            for (int r = 0; r < 4; r++){
                int m = m0 + wy * 32 + i * 16 + quad * 4 + r;
                C[(size_t)m * 1536 + n]       = f2bf(accP[i][j][r] + bv);
                C[(size_t)m * 1536 + 768 + n] = f2bf(accQ[i][j][r]);
            }
        }
    }
}

// ---------------- Attention v2: one block per (b,h,16-i group), K/V tiles in LDS ----------------
__global__ __launch_bounds__(128) void attn_k(const u16* __restrict__ qkv,
                                              const float* __restrict__ x,
                                              const float* __restrict__ eattr,
                                              const float* __restrict__ emask,
                                              const float* __restrict__ e1w, const float* __restrict__ e1b,
                                              const float* __restrict__ e2w, const float* __restrict__ e2b,
                                              u16* __restrict__ att){
    __shared__ u16 Ks[NN * 98];
    __shared__ u16 Vs[NN * 98];
    __shared__ float xs[NN * 3];
    __shared__ float qs[HD];
    __shared__ float ps[NN];
    __shared__ float red[2];
    const int tid = threadIdx.x;
    const int h = blockIdx.y, b = blockIdx.z;
    const int i0 = blockIdx.x * 16;

    for (int idx = tid; idx < NN * HD; idx += 128){
        int j = idx / HD, d = idx - j * HD;
        const u16* base = qkv + (size_t)(b * NN + j) * 2304 + h * HD + d;
        Ks[j * 98 + d] = base[DD];
        Vs[j * 98 + d] = base[1536];
    }
    if (tid < NN){
        xs[tid * 3]     = x[(b * NN + tid) * 3];
        xs[tid * 3 + 1] = x[(b * NN + tid) * 3 + 1];
        xs[tid * 3 + 2] = x[(b * NN + tid) * 3 + 2];
    }
    __syncthreads();
    const float w1r = e1w[h * 2], w1a = e1w[h * 2 + 1], b1 = e1b[h];
    const float w2r = e2w[h * 2], w2a = e2w[h * 2 + 1], b2v = e2b[h];
    const int wv = tid >> 6;

    for (int ig = 0; ig < 16; ig++){
        const int i = i0 + ig, ni = b * NN + i;
        if (tid < HD) qs[tid] = bf2f(qkv[(size_t)ni * 2304 + h * HD + tid]) * 0.10206207261596577f;
        __syncthreads();
        const int j = tid;
        float s = 0.f;
        #pragma unroll 8
        for (int d = 0; d < HD; d++) s += qs[d] * bf2f(Ks[j * 98 + d]);
        float d0 = xs[i * 3]     - xs[j * 3];
        float d1 = xs[i * 3 + 1] - xs[j * 3 + 1];
        float d2 = xs[i * 3 + 2] - xs[j * 3 + 2];
        float radial = d0*d0 + d1*d1 + d2*d2;
        int e = ni * NN + j;
        float at = eattr[e], em = emask[e];
        s += (w1r * radial + w1a * at + b1) * em;
        float gw = (w2r * radial + w2a * at + b2v) * em;
        float m1 = wred_max(s);
        if ((tid & 63) == 0) red[wv] = m1;
        __syncthreads();
        float M = fmaxf(red[0], red[1]);
        __syncthreads();
        float ev = __expf(s - M);
        float s1 = wred_sum(ev);
        if ((tid & 63) == 0) red[wv] = s1;
        __syncthreads();
        float S = red[0] + red[1];
        ps[j] = tanhf(gw) * ev / S;
        __syncthreads();
        if (tid < HD){
            float a = 0.f;
            #pragma unroll 8
            for (int jj = 0; jj < NN; jj++) a += ps[jj] * bf2f(Vs[jj * 98 + tid]);
            att[(size_t)ni * DD + h * HD + tid] = f2bf(a);
        }
        __syncthreads();
    }
}

// Extract c0/c1 columns of cm1_w (f32)
__global__ void prep_k(const float* __restrict__ cm1w, float* __restrict__ c01){
    int idx = blockIdx.x * 256 + threadIdx.x;
    if (idx < 768){
        c01[idx]       = cm1w[(size_t)idx * 1538 + 1536];
        c01[768 + idx] = cm1w[(size_t)idx * 1538 + 1537];
    }
}

// Convert f32 array -> bf16 (4 elems/thread)
__global__ void w2bf_k(const float* __restrict__ W, u16* __restrict__ O, int n){
    int i4 = (blockIdx.x * 256 + threadIdx.x) * 4;
    if (i4 < n){
        float4 v = *(const float4*)(W + i4);
        u16x4 o; o[0] = f2bf(v.x); o[1] = f2bf(v.y); o[2] = f2bf(v.z); o[3] = f2bf(v.w);
        *(u16x4*)&O[i4] = o;
    }
}

// ---------------- Edge MLP + coordinate aggregation (v8: cooperative LDS panels, dbuf) ----------------
// 512 threads, one block per (row r, half): M=64 edges. kk-outer/np-inner (T1 staged once
// per kk = staging VALU /3). BOTH operands staged cooperatively in LDS, double-buffered:
//   T1 panel 2 x (64x64)  = 18.4 KB   (silu, once per kk64)
//   B  panel 2 x (256x64) = 73.7 KB   (pure bf16 copy, per (kk64,np), 4 uint4/thread)
// One barrier per panel (36); prefetch of panel s+1 issued before MFMAs of panel s ->
// L2 latency paid once per panel across 512 threads' outstanding loads (Round 9 lesson:
// per-wave fragment fetch = serial latency chain). acc[3][2][4]=96 f32, np unrolled so
// all acc indices static (Round 6 spill lesson). ~94 KB LDS -> 1 block/CU, 8 waves.
__global__ __launch_bounds__(512, 2) void edge_k(const u16* __restrict__ PQ,
                                                 const u16* __restrict__ W2b,
                                                 const float* __restrict__ b2,
                                                 const float* __restrict__ w3,
                                                 const float* __restrict__ c01,
                                                 const float* __restrict__ x,
                                                 const float* __restrict__ eattr,
                                                 const float* __restrict__ emask,
                                                 float* __restrict__ aggpart){
    __shared__ u16 T1d[2][64 * 72];     // 18,432 B
    __shared__ u16 Bd[2][256 * 72];     // 73,728 B
    __shared__ float cdx[64], cdy[64], cdz[64], rad[64], eat[64], ems[64];
    __shared__ float sacc[64];
    const int tid = threadIdx.x;
    const int blk = blockIdx.x;
    const int r = blk >> 1, half = blk & 1;
    const int b = r >> 7;
    const int j0 = half * 64;

    if (tid < 64){
        int jg = j0 + tid;
        int nc = b * NN + jg;
        int e  = r * NN + jg;
        float d0 = x[r * 3]     - x[nc * 3];
        float d1 = x[r * 3 + 1] - x[nc * 3 + 1];
        float d2 = x[r * 3 + 2] - x[nc * 3 + 2];
        float radial = d0*d0 + d1*d1 + d2*d2;
        float inv = 1.f / (sqrtf(radial + 1e-8f) + 1.0f);   // NORM_CONST = 1
        cdx[tid] = d0 * inv; cdy[tid] = d1 * inv; cdz[tid] = d2 * inv;
        rad[tid] = radial; eat[tid] = eattr[e]; ems[tid] = emask[e];
        sacc[tid] = 0.f;
    }
    __syncthreads();

    // T1 K-panel (64 edges x 64 K), 1 u16x8/thread: silu(P[r]+Q[col]+rad*c0+attr*c1)
    auto stageT1 = [&](int kk, int p){
        int jl = tid >> 3, kc = tid & 7;
        int k = kc * 8;
        int nc = b * NN + j0 + jl;
        u16x8 qv = *(const u16x8*)(PQ + (size_t)nc * 1536 + 768 + kk + k);
        u16x8 pv = *(const u16x8*)(PQ + (size_t)r  * 1536 + kk + k);
        float4 c0a = *(const float4*)(c01 + kk + k);
        float4 c0b = *(const float4*)(c01 + kk + k + 4);
        float4 c1a = *(const float4*)(c01 + 768 + kk + k);
        float4 c1b = *(const float4*)(c01 + 768 + kk + k + 4);
        float c0r[8] = {c0a.x,c0a.y,c0a.z,c0a.w,c0b.x,c0b.y,c0b.z,c0b.w};
        float c1r[8] = {c1a.x,c1a.y,c1a.z,c1a.w,c1b.x,c1b.y,c1b.z,c1b.w};
        float rj = rad[jl], aj = eat[jl];
        u16x8 ov;
        #pragma unroll
        for (int t = 0; t < 8; t++){
            float f = bf2f(pv[t]) + bf2f(qv[t]) + rj * c0r[t] + aj * c1r[t];
            f = f / (1.f + __expf(-f));
            ov[t] = f2bf(f);
        }
        *(u16x8*)&T1d[p][jl * 72 + k] = ov;
    };
    // B panel (256 n x 64 K), pure copy from bf16 W2b: 4 uint4/thread
    auto stageB = [&](int np, int kk, int p){
        #pragma unroll
        for (int c = 0; c < 4; c++){
            int idx = c * 512 + tid;
            int row = idx >> 3, ch = idx & 7;
            *(uint4*)&Bd[p][row * 72 + ch * 8] =
                *(const uint4*)(W2b + (size_t)(np * 256 + row) * 768 + kk + ch * 8);
        }
    };

    const int w = tid >> 6, lane = tid & 63, quad = lane >> 4, l15 = lane & 15;
    const int wy = w >> 2, wx = w & 3;   // 2 row groups x 4 col groups
    f32x4 acc[3][2][4];
    #pragma unroll
    for (int np = 0; np < 3; np++)
        #pragma unroll
        for (int i = 0; i < 2; i++)
            #pragma unroll
            for (int jj = 0; jj < 4; jj++){ f32x4 z = {0.f,0.f,0.f,0.f}; acc[np][i][jj] = z; }

    stageT1(0, 0);
    stageB(0, 0, 0);
    __syncthreads();
    int buf = 0;
    for (int kk64 = 0; kk64 < 12; kk64++){
        const int t1b = kk64 & 1;
        #pragma unroll
        for (int np = 0; np < 3; np++){
            // prefetch next panel into alternate buffer (issued before this panel's MFMAs)
            if (np < 2){
                stageB(np + 1, kk64 * 64, buf ^ 1);
            } else if (kk64 < 11){
                stageB(0, (kk64 + 1) * 64, buf ^ 1);
                stageT1((kk64 + 1) * 64, t1b ^ 1);
            }
            #pragma unroll
            for (int k0 = 0; k0 < 64; k0 += 32){
                const int kq = k0 + quad * 8;
                bf16x8 aF[2], bF[4];
                #pragma unroll
                for (int i = 0; i < 2; i++) aF[i] = frag(&T1d[t1b][(wy * 32 + i * 16 + l15) * 72 + kq]);
                #pragma unroll
                for (int jj = 0; jj < 4; jj++)
                    bF[jj] = frag(&Bd[buf][(wx * 64 + jj * 16 + l15) * 72 + kq]);
                #pragma unroll
                for (int i = 0; i < 2; i++)
                    #pragma unroll
                    for (int jj = 0; jj < 4; jj++)
                        acc[np][i][jj] = mfma16(aF[i], bF[jj], acc[np][i][jj]);
            }
            __syncthreads();
            buf ^= 1;
        }
    }
    // fused epilogue: silu(t2raw) dot cm3 (b2/w3 from global, L1-hot)
    #pragma unroll
    for (int np = 0; np < 3; np++){
        float part[2][4];
        #pragma unroll
        for (int i = 0; i < 2; i++)
            #pragma unroll
            for (int rr = 0; rr < 4; rr++) part[i][rr] = 0.f;
        #pragma unroll
        for (int jj = 0; jj < 4; jj++){
            int n = np * 256 + wx * 64 + jj * 16 + l15;
            float bb = b2[n], cc = w3[n];
            #pragma unroll
            for (int i = 0; i < 2; i++)
                #pragma unroll
                for (int rr = 0; rr < 4; rr++){
                    float v = acc[np][i][jj][rr] + bb;
                    v = v / (1.f + __expf(-v));
                    part[i][rr] += v * cc;
                }
        }
        #pragma unroll
        for (int i = 0; i < 2; i++)
            #pragma unroll
            for (int rr = 0; rr < 4; rr++){
                float v = part[i][rr];
                v += __shfl_xor(v, 1); v += __shfl_xor(v, 2);
                v += __shfl_xor(v, 4); v += __shfl_xor(v, 8);
                if (l15 == 0) atomicAdd(&sacc[wy * 32 + i * 16 + quad * 4 + rr], v);
            }
    }
    __syncthreads();
    if (tid < 64){
        float sv = sacc[tid] * ems[tid];
        float tx = cdx[tid] * sv, ty = cdy[tid] * sv, tz = cdz[tid] * sv;
        #pragma unroll
        for (int m = 1; m < 64; m <<= 1){
            tx += __shfl_xor(tx, m); ty += __shfl_xor(ty, m); tz += __shfl_xor(tz, m);
        }
        if (tid == 0){
            aggpart[blk * 3 + 0] = tx;
            aggpart[blk * 3 + 1] = ty;
            aggpart[blk * 3 + 2] = tz;
        }
    }
}

__global__ void xout_k(const float* __restrict__ x, const float* __restrict__ linker,
                       const float* __restrict__ nodemask, const float* __restrict__ aggpart,
                       float* __restrict__ out){
    int idx = blockIdx.x * 256 + threadIdx.x;
    if (idx >= NNODE * 3) return;
    int node = idx / 3, c = idx - node * 3;
    float s = aggpart[(node * 2) * 3 + c] + aggpart[(node * 2 + 1) * 3 + c];
    out[(size_t)NNODE * DD + idx] = (x[idx] + s * 0.01f * linker[node]) * nodemask[node];
}

extern "C" void kernel_launch(void* const* d_in, const int* in_sizes, int n_in,
                              void* d_out, int out_size, void* d_ws, size_t ws_size,
                              hipStream_t stream){
    (void)in_sizes; (void)n_in; (void)out_size; (void)ws_size;
    const float* h        = (const float*)d_in[0];
    const float* x        = (const float*)d_in[1];
    const float* eattr    = (const float*)d_in[2];
    const float* nodemask = (const float*)d_in[3];
    const float* emask    = (const float*)d_in[4];
    const float* linker   = (const float*)d_in[5];
    const float* in_w  = (const float*)d_in[6];  const float* in_b  = (const float*)d_in[7];
    const float* out_w = (const float*)d_in[8];  const float* out_b = (const float*)d_in[9];
    const float* ln1s  = (const float*)d_in[10]; const float* ln1b  = (const float*)d_in[11];
    const float* ln2s  = (const float*)d_in[12]; const float* ln2b  = (const float*)d_in[13];
    const float* fc1w  = (const float*)d_in[14]; const float* fc1b  = (const float*)d_in[15];
    const float* fc2w  = (const float*)d_in[16]; const float* fc2b  = (const float*)d_in[17];
    const float* e1w   = (const float*)d_in[18]; const float* e1b   = (const float*)d_in[19];
    const float* e2w   = (const float*)d_in[20]; const float* e2b   = (const float*)d_in[21];
    const float* cm1w  = (const float*)d_in[22]; const float* cm1b  = (const float*)d_in[23];
    const float* cm2w  = (const float*)d_in[24]; const float* cm2b  = (const float*)d_in[25];
    const float* cm3w  = (const float*)d_in[26];
    // d_in[27] = edge_index (int32): fixed block structure (e = row*128 + j) — used implicitly.
    float* out = (float*)d_out;

    // Workspace layout (peak 7,471,104 B) — lifetimes disjoint:
    char* ws = (char*)d_ws;
    u16*   hn      = (u16*)  (ws + 0);         // [ln1 -> qkv gemm]
    u16*   qkv     = (u16*)  (ws + 786432);    // [qkv gemm -> attn]
    u16*   att     = (u16*)  (ws + 3145728);   // [attn -> proj gemm]
    float* h1f     = (float*)(ws + 0);         // [proj -> glu1]      (hn/qkv dead)
    u16*   ffin    = (u16*)  (ws + 1572864);   // [ln2 -> glu0]
    u16*   g1      = (u16*)  (ws + 2359296);   // [glu0 -> glu1]      (att dead)
    u16*   houtb   = (u16*)  (ws + 5505024);   // [glu1 -> pq gemm]
    u16*   PQ      = (u16*)  (ws + 0);         // [pq gemm -> edge]   (h1f dead)
    float* c01     = (float*)(ws + 1572864);   // [prep -> edge]      (ffin dead)
    float* aggpart = (float*)(ws + 1579008);   // [edge -> xout]      1024*3*4 = 12,288 B
    u16*   cm2b16  = (u16*)  (ws + 6291456);   // [w2bf -> edge]      1.18 MB

    ln_k       <<<NNODE, 256, 0, stream>>>(h, ln1s, ln1b, hn);
    gemm_bt    <<<dim3(2304/64, NNODE/64), 256, 0, stream>>>(hn, DD, in_w, DD, in_b, qkv, 2304, DD);
    attn_k     <<<dim3(NN/16, HH, BSZ), 128, 0, stream>>>(qkv, x, eattr, emask, e1w, e1b, e2w, e2b, att);
    gemm_proj  <<<dim3(DD/64, NNODE/64), 256, 0, stream>>>(att, out_w, out_b, h, h1f);
    ln_k       <<<NNODE, 256, 0, stream>>>(h1f, ln2s, ln2b, ffin);
    gemm_glu<0><<<dim3(FFN/64, NNODE/64), 256, 0, stream>>>(ffin, DD, fc1w, DD, fc1b, FFN, DD,
                                                            nullptr, nullptr, g1, FFN, nullptr);
    gemm_glu<1><<<dim3(DD/64, NNODE/64), 256, 0, stream>>>(g1, FFN, fc2w, FFN, fc2b, DD, FFN,
                                                           h1f, nodemask, houtb, DD, out);
    prep_k     <<<3, 256, 0, stream>>>(cm1w, c01);
    w2bf_k     <<<576, 256, 0, stream>>>(cm2w, cm2b16, DD*DD);
    gemm_pq    <<<dim3(DD/64, NNODE/64), 256, 0, stream>>>(houtb, cm1w, cm1b, PQ);
    edge_k     <<<1024, 512, 0, stream>>>(PQ, cm2b16, cm2b, cm3w, c01, x, eattr, emask, aggpart);
    xout_k     <<<6, 256, 0, stream>>>(x, linker, nodemask, aggpart, out);
}